// Round 1
// baseline (1278.186 us; speedup 1.0000x reference)
//
#include <hip/hip_runtime.h>
#include <hip/hip_bf16.h>
#include <math.h>

// GCN forward: log_softmax(spmm(relu(spmm(x@W1)+b1) @ W2) + b2)
// Round 4: gemm1 (x@W1, 50000x512 @ 512x128) was 531us of 1272us at
// MfmaUtil=0 (scalar VALU). Replace with bf16 MFMA (16x16x32):
//  - host gates on in_sizes[0] (bf16 => MFMA path, else old scalar fallback)
//  - W1^T pre-swizzled into global ws (XOR (c&7)<<3 on k) so blocks stage it
//    with LINEAR global_load_lds width=16 (guide rule 21), reads de-swizzle
//  - B frags = single ds_read_b128, conflict-free; A frags = 16B/lane global
//  - 256 blocks x 8 waves, 64KB LDS (W1^T in two K-halves), 2 row-tiles/wave
// Everything else (CSR build, spmm gathers, gemm2, fused softmax) unchanged.

#define N_NODES 50000
#define NFEAT   512
#define NHID    128
#define NCLASS  40
#define NEDGE   1600000

typedef unsigned short u16;
typedef __attribute__((ext_vector_type(8))) short bf16x8;
typedef __attribute__((ext_vector_type(4))) float f32x4;

__device__ __forceinline__ float ldf(const void* p, size_t i, int f32) {
    return f32 ? ((const float*)p)[i]
               : __bfloat162float(((const __hip_bfloat16*)p)[i]);
}

__global__ __launch_bounds__(256) void detect_kernel(
    const void* __restrict__ x, int* __restrict__ flag)
{
    __shared__ int bad;
    if (threadIdx.x == 0) bad = 0;
    __syncthreads();
    float v = __bfloat162float(((const __hip_bfloat16*)x)[threadIdx.x]);
    if (!(v > -100.f && v < 100.f)) atomicAdd(&bad, 1);
    __syncthreads();
    if (threadIdx.x == 0) *flag = (bad >= 4) ? 1 : 0;   // 1 => fp32
}

// ---- CSR build --------------------------------------------------------------

__global__ __launch_bounds__(256) void count_kernel(
    const int* __restrict__ edst, int* __restrict__ cnt)
{
    const int e = blockIdx.x * 256 + threadIdx.x;
    if (e < NEDGE) atomicAdd(&cnt[edst[e]], 1);
}

__global__ __launch_bounds__(1024) void scan_kernel(
    const int* __restrict__ cnt, int* __restrict__ row_ptr,
    int* __restrict__ wcur)
{
    __shared__ int part[1024];
    const int t = threadIdx.x;
    const int CH = (N_NODES + 1023) / 1024;   // 49
    const int base = t * CH;
    int s = 0;
    for (int i = 0; i < CH; ++i) {
        int idx = base + i;
        if (idx < N_NODES) s += cnt[idx];
    }
    part[t] = s;
    __syncthreads();
    for (int off = 1; off < 1024; off <<= 1) {
        int v = (t >= off) ? part[t - off] : 0;
        __syncthreads();
        part[t] += v;
        __syncthreads();
    }
    int run = part[t] - s;
    for (int i = 0; i < CH; ++i) {
        int idx = base + i;
        if (idx < N_NODES) {
            row_ptr[idx] = run;
            wcur[idx] = run;
            run += cnt[idx];
        }
    }
    if (t == 1023) row_ptr[N_NODES] = part[1023];
}

__global__ __launch_bounds__(256) void scatter_kernel(
    const int* __restrict__ esrc, const int* __restrict__ edst,
    const void* __restrict__ ev, int* __restrict__ wcur,
    int* __restrict__ src_s, float* __restrict__ val_s,
    const int* __restrict__ flag)
{
    const int f32 = *flag;
    const int e = blockIdx.x * 256 + threadIdx.x;
    if (e >= NEDGE) return;
    const int pos = atomicAdd(&wcur[edst[e]], 1);
    src_s[pos] = esrc[e];
    val_s[pos] = ldf(ev, e, f32);
}

// ---- gemm1: MFMA path (bf16 inputs) ----------------------------------------

// W1[512][128] bf16 -> Wt (two 32K-elem halves):
//   Wt[h*32768 + c*256 + ((k&255) ^ ((c&7)<<3))] = W1[k][c],  h = k>>8
__global__ __launch_bounds__(256) void w1t_prep_kernel(
    const u16* __restrict__ W1, u16* __restrict__ Wt)
{
    const int e = blockIdx.x * 256 + threadIdx.x;   // grid 256 -> 65536 elems
    const int k = e >> 7, c = e & 127;
    const int h = k >> 8, kl = k & 255;
    Wt[h * 32768 + c * 256 + (kl ^ ((c & 7) << 3))] = W1[e];
}

__device__ __forceinline__ void async16(const u16* g, u16* l) {
    __builtin_amdgcn_global_load_lds(
        (const __attribute__((address_space(1))) void*)g,
        (__attribute__((address_space(3))) void*)l, 16, 0, 0);
}

// 256 blocks x 512 threads. wave = 32 rows (2 x 16-row tiles), all 128 cols.
// chunk = blockIdx + 256*wave spreads the 1563 chunks evenly over blocks.
__global__ __launch_bounds__(512, 2) void gemm1_mfma_kernel(
    const u16* __restrict__ x, const u16* __restrict__ Wt,
    float* __restrict__ XW)
{
    __shared__ u16 w[32768];               // 64 KB: one K-half of W1^T (swizzled)
    const int tid  = threadIdx.x;
    const int wave = tid >> 6;
    const int lane = tid & 63;
    const int g    = lane >> 4;            // k-subgroup 0..3
    const int r16  = lane & 15;
    const int chunk = blockIdx.x + 256 * wave;
    const long row0 = (long)chunk * 32;
    const int  v0 = (row0 < N_NODES);          // rows are 16-aligned, 50000%16==0
    const int  v1 = (row0 + 16 < N_NODES);
    const int  swz = (r16 & 7) << 3;

    f32x4 acc0[8], acc1[8];
    #pragma unroll
    for (int c = 0; c < 8; ++c) {
        acc0[c] = (f32x4){0.f, 0.f, 0.f, 0.f};
        acc1[c] = (f32x4){0.f, 0.f, 0.f, 0.f};
    }

    for (int h = 0; h < 2; ++h) {
        if (h) __syncthreads();            // half0 reads done before overwrite
        #pragma unroll
        for (int s = 0; s < 8; ++s) {
            const int seg = wave + s * 8;  // 64 segments x 512 u16 (1 KB)
            async16(Wt + h * 32768 + seg * 512 + lane * 8, &w[seg * 512]);
        }
        __syncthreads();                   // drains vmcnt before ds_read

        if (v0) {
            #pragma unroll
            for (int tl = 0; tl < 8; ++tl) {
                const int t = h * 8 + tl;
                bf16x8 a0 = *(const bf16x8*)
                    (x + (size_t)(row0 + r16) * NFEAT + t * 32 + g * 8);
                bf16x8 a1 = {0, 0, 0, 0, 0, 0, 0, 0};
                if (v1) a1 = *(const bf16x8*)
                    (x + (size_t)(row0 + 16 + r16) * NFEAT + t * 32 + g * 8);
                const int kb = (tl * 32 + g * 8) ^ swz;
                #pragma unroll
                for (int c = 0; c < 8; ++c) {
                    const bf16x8 b = *(const bf16x8*)&w[(c * 16 + r16) * 256 + kb];
                    acc0[c] = __builtin_amdgcn_mfma_f32_16x16x32_bf16(
                        a0, b, acc0[c], 0, 0, 0);
                    acc1[c] = __builtin_amdgcn_mfma_f32_16x16x32_bf16(
                        a1, b, acc1[c], 0, 0, 0);
                }
            }
        }
    }

    // C/D layout (m89-verified): col = lane&15, row = (lane>>4)*4 + reg
    if (v0) {
        #pragma unroll
        for (int c = 0; c < 8; ++c)
            #pragma unroll
            for (int r = 0; r < 4; ++r)
                XW[(size_t)(row0 + g * 4 + r) * NHID + c * 16 + r16] = acc0[c][r];
    }
    if (v1) {
        #pragma unroll
        for (int c = 0; c < 8; ++c)
            #pragma unroll
            for (int r = 0; r < 4; ++r)
                XW[(size_t)(row0 + 16 + g * 4 + r) * NHID + c * 16 + r16] = acc1[c][r];
    }
}

// ---- gemm1: scalar fallback (non-bf16 inputs) ------------------------------

__global__ __launch_bounds__(128) void gemm1_kernel(
    const void* __restrict__ x,
    const void* __restrict__ W1,
    float* __restrict__ XW,
    const int* __restrict__ flag)
{
    __shared__ float xs[NFEAT];
    const int f32 = *flag;
    const int row = blockIdx.x;
    const int j = threadIdx.x;
    for (int k = j; k < NFEAT; k += 128)
        xs[k] = ldf(x, (size_t)row * NFEAT + k, f32);
    __syncthreads();
    float acc = 0.f;
    #pragma unroll 8
    for (int k = 0; k < NFEAT; ++k)
        acc += xs[k] * ldf(W1, (size_t)k * NHID + j, f32);
    XW[(size_t)row * NHID + j] = acc;
}

// ---- sparse + tail compute --------------------------------------------------

__global__ __launch_bounds__(256) void spmm1_gather_kernel(
    const int* __restrict__ row_ptr, const int* __restrict__ src_s,
    const float* __restrict__ val_s, const float* __restrict__ XW,
    const void* __restrict__ b1, float* __restrict__ H1,
    const int* __restrict__ flag)
{
    const int f32 = *flag;
    const int wave = threadIdx.x >> 6;
    const int lane = threadIdx.x & 63;
    const int row = blockIdx.x * 4 + wave;
    const int beg = row_ptr[row], end = row_ptr[row + 1];
    const float2* XW2 = (const float2*)XW;
    float2 acc = {0.f, 0.f};
    for (int j = beg; j < end; ++j) {
        const int s = src_s[j];
        const float v = val_s[j];
        const float2 xv = XW2[(size_t)s * 64 + lane];
        acc.x += v * xv.x;
        acc.y += v * xv.y;
    }
    acc.x = fmaxf(acc.x + ldf(b1, lane * 2 + 0, f32), 0.f);
    acc.y = fmaxf(acc.y + ldf(b1, lane * 2 + 1, f32), 0.f);
    ((float2*)H1)[(size_t)row * 64 + lane] = acc;
}

__global__ __launch_bounds__(256) void gemm2_kernel(
    const float* __restrict__ H1,
    const void* __restrict__ W2,
    float* __restrict__ HW,
    const int* __restrict__ flag)
{
    __shared__ float hs[4][NHID];
    const int f32 = *flag;
    const int wave = threadIdx.x >> 6;
    const int lane = threadIdx.x & 63;
    const int row = blockIdx.x * 4 + wave;
    const float2 h = ((const float2*)H1)[(size_t)row * 64 + lane];
    hs[wave][lane * 2 + 0] = h.x;
    hs[wave][lane * 2 + 1] = h.y;
    __syncthreads();
    if (lane < NCLASS) {
        float acc = 0.f;
        #pragma unroll 8
        for (int k = 0; k < NHID; ++k)
            acc += hs[wave][k] * ldf(W2, (size_t)k * NCLASS + lane, f32);
        HW[(size_t)row * NCLASS + lane] = acc;
    }
}

__global__ __launch_bounds__(256) void spmm2_gather_kernel(
    const int* __restrict__ row_ptr, const int* __restrict__ src_s,
    const float* __restrict__ val_s, const float* __restrict__ HW,
    const void* __restrict__ b2, void* __restrict__ out,
    const int* __restrict__ flag)
{
    const int f32 = *flag;
    const int wave = threadIdx.x >> 6;
    const int lane = threadIdx.x & 63;
    const int row = blockIdx.x * 4 + wave;
    const int beg = row_ptr[row], end = row_ptr[row + 1];
    float acc = 0.f;
    for (int j = beg; j < end; ++j) {
        const int s = src_s[j];
        const float v = val_s[j];
        if (lane < NCLASS) acc += v * HW[(size_t)s * NCLASS + lane];
    }
    const float logit = (lane < NCLASS) ? acc + ldf(b2, lane, f32) : -INFINITY;
    float m = logit;
    #pragma unroll
    for (int o = 32; o >= 1; o >>= 1) m = fmaxf(m, __shfl_xor(m, o));
    float ex = (lane < NCLASS) ? expf(logit - m) : 0.f;
    float sm = ex;
    #pragma unroll
    for (int o = 32; o >= 1; o >>= 1) sm += __shfl_xor(sm, o);
    if (lane < NCLASS) {
        const float r = logit - m - logf(sm);
        const size_t idx = (size_t)row * NCLASS + lane;
        if (f32) ((float*)out)[idx] = r;
        else     ((__hip_bfloat16*)out)[idx] = __float2bfloat16(r);
    }
}

extern "C" void kernel_launch(void* const* d_in, const int* in_sizes, int n_in,
                              void* d_out, int out_size, void* d_ws, size_t ws_size,
                              hipStream_t stream)
{
    const void* x   = d_in[0];
    const void* W1  = d_in[1];
    const void* b1  = d_in[2];
    const void* W2  = d_in[3];
    const void* b2  = d_in[4];
    const int* esrc = (const int*)d_in[5];
    const int* edst = (const int*)d_in[6];
    const void* ev  = d_in[7];

    // workspace layout (floats/ints are both 4 B)
    float* XW      = (float*)d_ws;                         // N*NHID      (25.6 MB)
    float* H1      = XW + (size_t)N_NODES * NHID;          // N*NHID      (25.6 MB)
    float* HW      = H1 + (size_t)N_NODES * NHID;          // N*NCLASS    ( 8.0 MB)
    float* val_s   = HW + (size_t)N_NODES * NCLASS;        // NEDGE       ( 6.4 MB)
    int*   src_s   = (int*)(val_s + NEDGE);                // NEDGE       ( 6.4 MB)
    int*   cnt     = src_s + NEDGE;                        // N           ( 0.2 MB)
    int*   row_ptr = cnt + N_NODES;                        // N+1
    int*   wcur    = row_ptr + N_NODES + 1;                // N
    int*   FLAG    = wcur + N_NODES;                       // 1

    // Swizzled W1^T (128 KB) parked in the HW region: written by w1t_prep,
    // consumed by gemm1_mfma, both strictly before gemm2 writes HW. 16B-aligned
    // (HW sits at a 51.2 MB offset).
    u16* Wt_g = (u16*)HW;

    // bf16 detection for the host-side kernel choice (device FLAG still feeds
    // the dtype-agnostic loads elsewhere). Fallback on anything unexpected.
    const bool x_bf16 = (n_in >= 8) && (in_sizes[0] == N_NODES * NFEAT * 2);

    (void)hipMemsetAsync(cnt, 0, (size_t)N_NODES * sizeof(int), stream);

    detect_kernel<<<1, 256, 0, stream>>>(x, FLAG);

    if (x_bf16)
        w1t_prep_kernel<<<256, 256, 0, stream>>>((const u16*)W1, Wt_g);

    count_kernel<<<NEDGE / 256, 256, 0, stream>>>(edst, cnt);
    scan_kernel<<<1, 1024, 0, stream>>>(cnt, row_ptr, wcur);
    scatter_kernel<<<NEDGE / 256, 256, 0, stream>>>(esrc, edst, ev, wcur,
                                                    src_s, val_s, FLAG);

    if (x_bf16)
        gemm1_mfma_kernel<<<256, 512, 0, stream>>>((const u16*)x, Wt_g, XW);
    else
        gemm1_kernel<<<N_NODES, 128, 0, stream>>>(x, W1, XW, FLAG);

    spmm1_gather_kernel<<<N_NODES / 4, 256, 0, stream>>>(row_ptr, src_s, val_s,
                                                         XW, b1, H1, FLAG);

    gemm2_kernel<<<N_NODES / 4, 256, 0, stream>>>(H1, W2, HW, FLAG);

    spmm2_gather_kernel<<<N_NODES / 4, 256, 0, stream>>>(row_ptr, src_s, val_s,
                                                         HW, b2, d_out, FLAG);
}

// Round 2
// 1257.876 us; speedup vs baseline: 1.0161x; 1.0161x over previous
//
#include <hip/hip_runtime.h>
#include <hip/hip_bf16.h>
#include <math.h>

// GCN forward: log_softmax(spmm(relu(spmm(x@W1)+b1) @ W2) + b2)
// Round 5: round-4's MFMA gemm1 never ran -- the host-side in_sizes gate
// failed (in_sizes is not bytes). Gate on the device-side dtype FLAG instead:
//  - w1t_prep + gemm1_mfma early-return when flag!=0 (fp32)
//  - scalar gemm1 fallback early-returns when flag==0, and is now grid-stride
//    (4096 blocks) so the bf16-path early-out costs ~nothing
// MFMA gemm1 design (round 4): bf16 16x16x32, W1^T pre-swizzled in global ws,
// linear global_load_lds width=16 staging, swizzled ds_read_b128 B-frags,
// 256 blocks x 8 waves, 2 row-tiles/wave, fp32 accum.

#define N_NODES 50000
#define NFEAT   512
#define NHID    128
#define NCLASS  40
#define NEDGE   1600000

typedef unsigned short u16;
typedef __attribute__((ext_vector_type(8))) short bf16x8;
typedef __attribute__((ext_vector_type(4))) float f32x4;

__device__ __forceinline__ float ldf(const void* p, size_t i, int f32) {
    return f32 ? ((const float*)p)[i]
               : __bfloat162float(((const __hip_bfloat16*)p)[i]);
}

__global__ __launch_bounds__(256) void detect_kernel(
    const void* __restrict__ x, int* __restrict__ flag)
{
    __shared__ int bad;
    if (threadIdx.x == 0) bad = 0;
    __syncthreads();
    float v = __bfloat162float(((const __hip_bfloat16*)x)[threadIdx.x]);
    if (!(v > -100.f && v < 100.f)) atomicAdd(&bad, 1);
    __syncthreads();
    if (threadIdx.x == 0) *flag = (bad >= 4) ? 1 : 0;   // 1 => fp32
}

// ---- CSR build --------------------------------------------------------------

__global__ __launch_bounds__(256) void count_kernel(
    const int* __restrict__ edst, int* __restrict__ cnt)
{
    const int e = blockIdx.x * 256 + threadIdx.x;
    if (e < NEDGE) atomicAdd(&cnt[edst[e]], 1);
}

__global__ __launch_bounds__(1024) void scan_kernel(
    const int* __restrict__ cnt, int* __restrict__ row_ptr,
    int* __restrict__ wcur)
{
    __shared__ int part[1024];
    const int t = threadIdx.x;
    const int CH = (N_NODES + 1023) / 1024;   // 49
    const int base = t * CH;
    int s = 0;
    for (int i = 0; i < CH; ++i) {
        int idx = base + i;
        if (idx < N_NODES) s += cnt[idx];
    }
    part[t] = s;
    __syncthreads();
    for (int off = 1; off < 1024; off <<= 1) {
        int v = (t >= off) ? part[t - off] : 0;
        __syncthreads();
        part[t] += v;
        __syncthreads();
    }
    int run = part[t] - s;
    for (int i = 0; i < CH; ++i) {
        int idx = base + i;
        if (idx < N_NODES) {
            row_ptr[idx] = run;
            wcur[idx] = run;
            run += cnt[idx];
        }
    }
    if (t == 1023) row_ptr[N_NODES] = part[1023];
}

__global__ __launch_bounds__(256) void scatter_kernel(
    const int* __restrict__ esrc, const int* __restrict__ edst,
    const void* __restrict__ ev, int* __restrict__ wcur,
    int* __restrict__ src_s, float* __restrict__ val_s,
    const int* __restrict__ flag)
{
    const int f32 = *flag;
    const int e = blockIdx.x * 256 + threadIdx.x;
    if (e >= NEDGE) return;
    const int pos = atomicAdd(&wcur[edst[e]], 1);
    src_s[pos] = esrc[e];
    val_s[pos] = ldf(ev, e, f32);
}

// ---- gemm1: MFMA path (bf16 inputs, device-flag gated) ----------------------

// W1[512][128] bf16 -> Wt (two 32K-elem halves):
//   Wt[h*32768 + c*256 + ((k&255) ^ ((c&7)<<3))] = W1[k][c],  h = k>>8
__global__ __launch_bounds__(256) void w1t_prep_kernel(
    const u16* __restrict__ W1, u16* __restrict__ Wt,
    const int* __restrict__ flag)
{
    if (*flag) return;                              // fp32 path: not used
    const int e = blockIdx.x * 256 + threadIdx.x;   // grid 256 -> 65536 elems
    const int k = e >> 7, c = e & 127;
    const int h = k >> 8, kl = k & 255;
    Wt[h * 32768 + c * 256 + (kl ^ ((c & 7) << 3))] = W1[e];
}

__device__ __forceinline__ void async16(const u16* g, u16* l) {
    __builtin_amdgcn_global_load_lds(
        (const __attribute__((address_space(1))) void*)g,
        (__attribute__((address_space(3))) void*)l, 16, 0, 0);
}

// 256 blocks x 512 threads. wave = 32 rows (2 x 16-row tiles), all 128 cols.
// chunk = blockIdx + 256*wave spreads the 1563 chunks evenly over blocks.
__global__ __launch_bounds__(512, 2) void gemm1_mfma_kernel(
    const u16* __restrict__ x, const u16* __restrict__ Wt,
    float* __restrict__ XW, const int* __restrict__ flag)
{
    if (*flag) return;                     // fp32 path handled by scalar kernel
    __shared__ u16 w[32768];               // 64 KB: one K-half of W1^T (swizzled)
    const int tid  = threadIdx.x;
    const int wave = tid >> 6;
    const int lane = tid & 63;
    const int g    = lane >> 4;            // k-subgroup 0..3
    const int r16  = lane & 15;
    const int chunk = blockIdx.x + 256 * wave;
    const long row0 = (long)chunk * 32;
    const int  v0 = (row0 < N_NODES);          // 50000 = 32*1562 + 16
    const int  v1 = (row0 + 16 < N_NODES);
    const int  swz = (r16 & 7) << 3;

    f32x4 acc0[8], acc1[8];
    #pragma unroll
    for (int c = 0; c < 8; ++c) {
        acc0[c] = (f32x4){0.f, 0.f, 0.f, 0.f};
        acc1[c] = (f32x4){0.f, 0.f, 0.f, 0.f};
    }

    for (int h = 0; h < 2; ++h) {
        if (h) __syncthreads();            // half0 reads done before overwrite
        #pragma unroll
        for (int s = 0; s < 8; ++s) {
            const int seg = wave + s * 8;  // 64 segments x 512 u16 (1 KB)
            async16(Wt + h * 32768 + seg * 512 + lane * 8, &w[seg * 512]);
        }
        __syncthreads();                   // drains vmcnt before ds_read

        if (v0) {
            #pragma unroll
            for (int tl = 0; tl < 8; ++tl) {
                const int t = h * 8 + tl;
                bf16x8 a0 = *(const bf16x8*)
                    (x + (size_t)(row0 + r16) * NFEAT + t * 32 + g * 8);
                bf16x8 a1 = {0, 0, 0, 0, 0, 0, 0, 0};
                if (v1) a1 = *(const bf16x8*)
                    (x + (size_t)(row0 + 16 + r16) * NFEAT + t * 32 + g * 8);
                const int kb = (tl * 32 + g * 8) ^ swz;
                #pragma unroll
                for (int c = 0; c < 8; ++c) {
                    const bf16x8 b = *(const bf16x8*)&w[(c * 16 + r16) * 256 + kb];
                    acc0[c] = __builtin_amdgcn_mfma_f32_16x16x32_bf16(
                        a0, b, acc0[c], 0, 0, 0);
                    acc1[c] = __builtin_amdgcn_mfma_f32_16x16x32_bf16(
                        a1, b, acc1[c], 0, 0, 0);
                }
            }
        }
    }

    // C/D layout (m89-verified): col = lane&15, row = (lane>>4)*4 + reg
    if (v0) {
        #pragma unroll
        for (int c = 0; c < 8; ++c)
            #pragma unroll
            for (int r = 0; r < 4; ++r)
                XW[(size_t)(row0 + g * 4 + r) * NHID + c * 16 + r16] = acc0[c][r];
    }
    if (v1) {
        #pragma unroll
        for (int c = 0; c < 8; ++c)
            #pragma unroll
            for (int r = 0; r < 4; ++r)
                XW[(size_t)(row0 + 16 + g * 4 + r) * NHID + c * 16 + r16] = acc1[c][r];
    }
}

// ---- gemm1: scalar fallback (fp32 inputs, device-flag gated) ---------------
// Grid-stride (4096 blocks) so the bf16-path early-out is cheap.

__global__ __launch_bounds__(128) void gemm1_kernel(
    const void* __restrict__ x,
    const void* __restrict__ W1,
    float* __restrict__ XW,
    const int* __restrict__ flag)
{
    if (*flag == 0) return;                // bf16 path handled by MFMA kernel
    __shared__ float xs[NFEAT];
    const int j = threadIdx.x;
    for (int row = blockIdx.x; row < N_NODES; row += gridDim.x) {
        __syncthreads();
        for (int k = j; k < NFEAT; k += 128)
            xs[k] = ldf(x, (size_t)row * NFEAT + k, 1);
        __syncthreads();
        float acc = 0.f;
        #pragma unroll 8
        for (int k = 0; k < NFEAT; ++k)
            acc += xs[k] * ldf(W1, (size_t)k * NHID + j, 1);
        XW[(size_t)row * NHID + j] = acc;
    }
}

// ---- sparse + tail compute --------------------------------------------------

__global__ __launch_bounds__(256) void spmm1_gather_kernel(
    const int* __restrict__ row_ptr, const int* __restrict__ src_s,
    const float* __restrict__ val_s, const float* __restrict__ XW,
    const void* __restrict__ b1, float* __restrict__ H1,
    const int* __restrict__ flag)
{
    const int f32 = *flag;
    const int wave = threadIdx.x >> 6;
    const int lane = threadIdx.x & 63;
    const int row = blockIdx.x * 4 + wave;
    const int beg = row_ptr[row], end = row_ptr[row + 1];
    const float2* XW2 = (const float2*)XW;
    float2 acc = {0.f, 0.f};
    for (int j = beg; j < end; ++j) {
        const int s = src_s[j];
        const float v = val_s[j];
        const float2 xv = XW2[(size_t)s * 64 + lane];
        acc.x += v * xv.x;
        acc.y += v * xv.y;
    }
    acc.x = fmaxf(acc.x + ldf(b1, lane * 2 + 0, f32), 0.f);
    acc.y = fmaxf(acc.y + ldf(b1, lane * 2 + 1, f32), 0.f);
    ((float2*)H1)[(size_t)row * 64 + lane] = acc;
}

__global__ __launch_bounds__(256) void gemm2_kernel(
    const float* __restrict__ H1,
    const void* __restrict__ W2,
    float* __restrict__ HW,
    const int* __restrict__ flag)
{
    __shared__ float hs[4][NHID];
    const int f32 = *flag;
    const int wave = threadIdx.x >> 6;
    const int lane = threadIdx.x & 63;
    const int row = blockIdx.x * 4 + wave;
    const float2 h = ((const float2*)H1)[(size_t)row * 64 + lane];
    hs[wave][lane * 2 + 0] = h.x;
    hs[wave][lane * 2 + 1] = h.y;
    __syncthreads();
    if (lane < NCLASS) {
        float acc = 0.f;
        #pragma unroll 8
        for (int k = 0; k < NHID; ++k)
            acc += hs[wave][k] * ldf(W2, (size_t)k * NCLASS + lane, f32);
        HW[(size_t)row * NCLASS + lane] = acc;
    }
}

__global__ __launch_bounds__(256) void spmm2_gather_kernel(
    const int* __restrict__ row_ptr, const int* __restrict__ src_s,
    const float* __restrict__ val_s, const float* __restrict__ HW,
    const void* __restrict__ b2, void* __restrict__ out,
    const int* __restrict__ flag)
{
    const int f32 = *flag;
    const int wave = threadIdx.x >> 6;
    const int lane = threadIdx.x & 63;
    const int row = blockIdx.x * 4 + wave;
    const int beg = row_ptr[row], end = row_ptr[row + 1];
    float acc = 0.f;
    for (int j = beg; j < end; ++j) {
        const int s = src_s[j];
        const float v = val_s[j];
        if (lane < NCLASS) acc += v * HW[(size_t)s * NCLASS + lane];
    }
    const float logit = (lane < NCLASS) ? acc + ldf(b2, lane, f32) : -INFINITY;
    float m = logit;
    #pragma unroll
    for (int o = 32; o >= 1; o >>= 1) m = fmaxf(m, __shfl_xor(m, o));
    float ex = (lane < NCLASS) ? expf(logit - m) : 0.f;
    float sm = ex;
    #pragma unroll
    for (int o = 32; o >= 1; o >>= 1) sm += __shfl_xor(sm, o);
    if (lane < NCLASS) {
        const float r = logit - m - logf(sm);
        const size_t idx = (size_t)row * NCLASS + lane;
        if (f32) ((float*)out)[idx] = r;
        else     ((__hip_bfloat16*)out)[idx] = __float2bfloat16(r);
    }
}

extern "C" void kernel_launch(void* const* d_in, const int* in_sizes, int n_in,
                              void* d_out, int out_size, void* d_ws, size_t ws_size,
                              hipStream_t stream)
{
    const void* x   = d_in[0];
    const void* W1  = d_in[1];
    const void* b1  = d_in[2];
    const void* W2  = d_in[3];
    const void* b2  = d_in[4];
    const int* esrc = (const int*)d_in[5];
    const int* edst = (const int*)d_in[6];
    const void* ev  = d_in[7];

    // workspace layout (floats/ints are both 4 B)
    float* XW      = (float*)d_ws;                         // N*NHID      (25.6 MB)
    float* H1      = XW + (size_t)N_NODES * NHID;          // N*NHID      (25.6 MB)
    float* HW      = H1 + (size_t)N_NODES * NHID;          // N*NCLASS    ( 8.0 MB)
    float* val_s   = HW + (size_t)N_NODES * NCLASS;        // NEDGE       ( 6.4 MB)
    int*   src_s   = (int*)(val_s + NEDGE);                // NEDGE       ( 6.4 MB)
    int*   cnt     = src_s + NEDGE;                        // N           ( 0.2 MB)
    int*   row_ptr = cnt + N_NODES;                        // N+1
    int*   wcur    = row_ptr + N_NODES + 1;                // N
    int*   FLAG    = wcur + N_NODES;                       // 1

    // Swizzled W1^T (128 KB) parked in the HW region: written by w1t_prep,
    // consumed by gemm1_mfma, both strictly before gemm2 writes HW.
    u16* Wt_g = (u16*)HW;

    (void)hipMemsetAsync(cnt, 0, (size_t)N_NODES * sizeof(int), stream);

    detect_kernel<<<1, 256, 0, stream>>>(x, FLAG);

    w1t_prep_kernel<<<256, 256, 0, stream>>>((const u16*)W1, Wt_g, FLAG);

    count_kernel<<<NEDGE / 256, 256, 0, stream>>>(edst, cnt);
    scan_kernel<<<1, 1024, 0, stream>>>(cnt, row_ptr, wcur);
    scatter_kernel<<<NEDGE / 256, 256, 0, stream>>>(esrc, edst, ev, wcur,
                                                    src_s, val_s, FLAG);

    gemm1_mfma_kernel<<<256, 512, 0, stream>>>((const u16*)x, Wt_g, XW, FLAG);
    gemm1_kernel<<<4096, 128, 0, stream>>>(x, W1, XW, FLAG);

    spmm1_gather_kernel<<<N_NODES / 4, 256, 0, stream>>>(row_ptr, src_s, val_s,
                                                         XW, b1, H1, FLAG);

    gemm2_kernel<<<N_NODES / 4, 256, 0, stream>>>(H1, W2, HW, FLAG);

    spmm2_gather_kernel<<<N_NODES / 4, 256, 0, stream>>>(row_ptr, src_s, val_s,
                                                         HW, b2, d_out, FLAG);
}

// Round 3
// 837.430 us; speedup vs baseline: 1.5263x; 1.5021x over previous
//
#include <hip/hip_runtime.h>
#include <hip/hip_bf16.h>
#include <math.h>

// GCN forward: log_softmax(spmm(relu(spmm(x@W1)+b1) @ W2) + b2)
// Round 6: inputs are FP32 (round-5 counters: scalar gemm1 ran full GEMM,
// flag==1). CDNA4 has no fp32 MFMA, so gemm1 now uses SPLIT-BF16 MFMA:
//   x ~= x_hi + x_lo, W ~= W_hi + W_lo  (bf16 each, lo = bf16(v - hi))
//   x@W ~= x_hi W_hi + x_lo W_hi + x_hi W_lo   (fp32 accum, ~2^-17 rel err)
// W1 pre-split+pre-swizzled to global ws; staged per K-quarter (32KB hi +
// 32KB lo LDS) via linear global_load_lds w=16; B-frags via swizzled
// ds_read_b128; x split in-register from float4 loads. Scalar gemm1 deleted.
// bf16-input case handled by the same kernel (lo terms skipped, uniform branch).

#define N_NODES 50000
#define NFEAT   512
#define NHID    128
#define NCLASS  40
#define NEDGE   1600000

typedef unsigned short u16;
typedef __attribute__((ext_vector_type(8))) short bf16x8;
typedef __attribute__((ext_vector_type(4))) float f32x4;

__device__ __forceinline__ float ldf(const void* p, size_t i, int f32) {
    return f32 ? ((const float*)p)[i]
               : __bfloat162float(((const __hip_bfloat16*)p)[i]);
}

__global__ __launch_bounds__(256) void detect_kernel(
    const void* __restrict__ x, int* __restrict__ flag)
{
    __shared__ int bad;
    if (threadIdx.x == 0) bad = 0;
    __syncthreads();
    float v = __bfloat162float(((const __hip_bfloat16*)x)[threadIdx.x]);
    if (!(v > -100.f && v < 100.f)) atomicAdd(&bad, 1);
    __syncthreads();
    if (threadIdx.x == 0) *flag = (bad >= 4) ? 1 : 0;   // 1 => fp32
}

// ---- CSR build --------------------------------------------------------------

__global__ __launch_bounds__(256) void count_kernel(
    const int* __restrict__ edst, int* __restrict__ cnt)
{
    const int e = blockIdx.x * 256 + threadIdx.x;
    if (e < NEDGE) atomicAdd(&cnt[edst[e]], 1);
}

__global__ __launch_bounds__(1024) void scan_kernel(
    const int* __restrict__ cnt, int* __restrict__ row_ptr,
    int* __restrict__ wcur)
{
    __shared__ int part[1024];
    const int t = threadIdx.x;
    const int CH = (N_NODES + 1023) / 1024;   // 49
    const int base = t * CH;
    int s = 0;
    for (int i = 0; i < CH; ++i) {
        int idx = base + i;
        if (idx < N_NODES) s += cnt[idx];
    }
    part[t] = s;
    __syncthreads();
    for (int off = 1; off < 1024; off <<= 1) {
        int v = (t >= off) ? part[t - off] : 0;
        __syncthreads();
        part[t] += v;
        __syncthreads();
    }
    int run = part[t] - s;
    for (int i = 0; i < CH; ++i) {
        int idx = base + i;
        if (idx < N_NODES) {
            row_ptr[idx] = run;
            wcur[idx] = run;
            run += cnt[idx];
        }
    }
    if (t == 1023) row_ptr[N_NODES] = part[1023];
}

__global__ __launch_bounds__(256) void scatter_kernel(
    const int* __restrict__ esrc, const int* __restrict__ edst,
    const void* __restrict__ ev, int* __restrict__ wcur,
    int* __restrict__ src_s, float* __restrict__ val_s,
    const int* __restrict__ flag)
{
    const int f32 = *flag;
    const int e = blockIdx.x * 256 + threadIdx.x;
    if (e >= NEDGE) return;
    const int pos = atomicAdd(&wcur[edst[e]], 1);
    src_s[pos] = esrc[e];
    val_s[pos] = ldf(ev, e, f32);
}

// ---- gemm1: split-bf16 MFMA -------------------------------------------------

// W1[512][128] (f32 or bf16) -> Wt_hi/Wt_lo, swizzled per K-quarter:
//   Wt[q*16384 + c*128 + ((k&127) ^ ((c&7)<<3))] = split(W1[k][c]), q = k>>7
__global__ __launch_bounds__(256) void w1t_prep_kernel(
    const void* __restrict__ W1, u16* __restrict__ Wt_hi,
    u16* __restrict__ Wt_lo, const int* __restrict__ flag)
{
    const int f32 = *flag;
    const int e = blockIdx.x * 256 + threadIdx.x;   // grid 256 -> 65536 elems
    const int k = e >> 7, c = e & 127;
    const int q = k >> 7, kq = k & 127;
    const float v = ldf(W1, e, f32);
    __hip_bfloat16 h = __float2bfloat16(v);
    __hip_bfloat16 l = __float2bfloat16(v - __bfloat162float(h));
    const int idx = q * 16384 + c * 128 + (kq ^ ((c & 7) << 3));
    Wt_hi[idx] = *(const u16*)&h;
    Wt_lo[idx] = *(const u16*)&l;
}

__device__ __forceinline__ void async16(const u16* g, u16* l) {
    __builtin_amdgcn_global_load_lds(
        (const __attribute__((address_space(1))) void*)g,
        (__attribute__((address_space(3))) void*)l, 16, 0, 0);
}

__device__ __forceinline__ void split8(const float* p, bf16x8& hi, bf16x8& lo) {
    float t[8];
    *(float4*)&t[0] = *(const float4*)p;
    *(float4*)&t[4] = *(const float4*)(p + 4);
    #pragma unroll
    for (int j = 0; j < 8; ++j) {
        __hip_bfloat16 h = __float2bfloat16(t[j]);
        float r = t[j] - __bfloat162float(h);
        __hip_bfloat16 l = __float2bfloat16(r);
        hi[j] = *(const short*)&h;
        lo[j] = *(const short*)&l;
    }
}

// 256 blocks x 512 threads (8 waves). wave = 32 rows (2 x 16-row tiles),
// all 128 cols. chunk = blockIdx + 256*wave covers ceil(50000/32)=1563 chunks.
__global__ __launch_bounds__(512) void gemm1_mfma_kernel(
    const void* __restrict__ x, const u16* __restrict__ Wt_hi,
    const u16* __restrict__ Wt_lo, float* __restrict__ XW,
    const int* __restrict__ flag)
{
    __shared__ u16 whi[16384];             // 32 KB: K-quarter of W_hi^T (swz)
    __shared__ u16 wlo[16384];             // 32 KB: K-quarter of W_lo^T (swz)
    const int f32  = *flag;
    const int tid  = threadIdx.x;
    const int wave = tid >> 6;
    const int lane = tid & 63;
    const int g    = lane >> 4;            // k-subgroup 0..3
    const int r16  = lane & 15;
    const int chunk = blockIdx.x + 256 * wave;
    const long row0 = (long)chunk * 32;
    const int  v0 = (row0 < N_NODES);          // 50000 = 32*1562 + 16
    const int  v1 = (row0 + 16 < N_NODES);
    const int  swz = (r16 & 7) << 3;
    const float* xf = (const float*)x;
    const u16*   xb = (const u16*)x;

    f32x4 acc0[8], acc1[8];
    #pragma unroll
    for (int c = 0; c < 8; ++c) {
        acc0[c] = (f32x4){0.f, 0.f, 0.f, 0.f};
        acc1[c] = (f32x4){0.f, 0.f, 0.f, 0.f};
    }

    for (int q = 0; q < 4; ++q) {
        if (q) __syncthreads();            // prev-quarter reads done
        #pragma unroll
        for (int s = 0; s < 4; ++s) {
            const int seg = wave + s * 8;  // 32 segments x 512 u16 (1 KB)
            async16(Wt_hi + q * 16384 + seg * 512 + lane * 8, &whi[seg * 512]);
            async16(Wt_lo + q * 16384 + seg * 512 + lane * 8, &wlo[seg * 512]);
        }
        __syncthreads();                   // drains vmcnt before ds_read

        if (v0) {
            #pragma unroll
            for (int tl = 0; tl < 4; ++tl) {
                const int kq = tl * 32 + g * 8;          // k within quarter
                const size_t kO = (size_t)q * 128 + kq;  // k within 512
                bf16x8 a0h = {0,0,0,0,0,0,0,0}, a0l = {0,0,0,0,0,0,0,0};
                bf16x8 a1h = {0,0,0,0,0,0,0,0}, a1l = {0,0,0,0,0,0,0,0};
                if (f32) {
                    split8(xf + (size_t)(row0 + r16) * NFEAT + kO, a0h, a0l);
                    if (v1)
                        split8(xf + (size_t)(row0 + 16 + r16) * NFEAT + kO,
                               a1h, a1l);
                } else {
                    a0h = *(const bf16x8*)(xb + (size_t)(row0 + r16) * NFEAT + kO);
                    if (v1)
                        a1h = *(const bf16x8*)
                            (xb + (size_t)(row0 + 16 + r16) * NFEAT + kO);
                }
                const int kb = kq ^ swz;
                #pragma unroll
                for (int c = 0; c < 8; ++c) {
                    const bf16x8 bh = *(const bf16x8*)&whi[(c * 16 + r16) * 128 + kb];
                    acc0[c] = __builtin_amdgcn_mfma_f32_16x16x32_bf16(
                        a0h, bh, acc0[c], 0, 0, 0);
                    acc1[c] = __builtin_amdgcn_mfma_f32_16x16x32_bf16(
                        a1h, bh, acc1[c], 0, 0, 0);
                    if (f32) {
                        const bf16x8 bl = *(const bf16x8*)&wlo[(c * 16 + r16) * 128 + kb];
                        acc0[c] = __builtin_amdgcn_mfma_f32_16x16x32_bf16(
                            a0l, bh, acc0[c], 0, 0, 0);
                        acc0[c] = __builtin_amdgcn_mfma_f32_16x16x32_bf16(
                            a0h, bl, acc0[c], 0, 0, 0);
                        acc1[c] = __builtin_amdgcn_mfma_f32_16x16x32_bf16(
                            a1l, bh, acc1[c], 0, 0, 0);
                        acc1[c] = __builtin_amdgcn_mfma_f32_16x16x32_bf16(
                            a1h, bl, acc1[c], 0, 0, 0);
                    }
                }
            }
        }
    }

    // C/D layout (m89-verified): col = lane&15, row = (lane>>4)*4 + reg
    if (v0) {
        #pragma unroll
        for (int c = 0; c < 8; ++c)
            #pragma unroll
            for (int r = 0; r < 4; ++r)
                XW[(size_t)(row0 + g * 4 + r) * NHID + c * 16 + r16] = acc0[c][r];
    }
    if (v1) {
        #pragma unroll
        for (int c = 0; c < 8; ++c)
            #pragma unroll
            for (int r = 0; r < 4; ++r)
                XW[(size_t)(row0 + 16 + g * 4 + r) * NHID + c * 16 + r16] = acc1[c][r];
    }
}

// ---- sparse + tail compute --------------------------------------------------

__global__ __launch_bounds__(256) void spmm1_gather_kernel(
    const int* __restrict__ row_ptr, const int* __restrict__ src_s,
    const float* __restrict__ val_s, const float* __restrict__ XW,
    const void* __restrict__ b1, float* __restrict__ H1,
    const int* __restrict__ flag)
{
    const int f32 = *flag;
    const int wave = threadIdx.x >> 6;
    const int lane = threadIdx.x & 63;
    const int row = blockIdx.x * 4 + wave;
    const int beg = row_ptr[row], end = row_ptr[row + 1];
    const float2* XW2 = (const float2*)XW;
    float2 acc = {0.f, 0.f};
    for (int j = beg; j < end; ++j) {
        const int s = src_s[j];
        const float v = val_s[j];
        const float2 xv = XW2[(size_t)s * 64 + lane];
        acc.x += v * xv.x;
        acc.y += v * xv.y;
    }
    acc.x = fmaxf(acc.x + ldf(b1, lane * 2 + 0, f32), 0.f);
    acc.y = fmaxf(acc.y + ldf(b1, lane * 2 + 1, f32), 0.f);
    ((float2*)H1)[(size_t)row * 64 + lane] = acc;
}

__global__ __launch_bounds__(256) void gemm2_kernel(
    const float* __restrict__ H1,
    const void* __restrict__ W2,
    float* __restrict__ HW,
    const int* __restrict__ flag)
{
    __shared__ float hs[4][NHID];
    const int f32 = *flag;
    const int wave = threadIdx.x >> 6;
    const int lane = threadIdx.x & 63;
    const int row = blockIdx.x * 4 + wave;
    const float2 h = ((const float2*)H1)[(size_t)row * 64 + lane];
    hs[wave][lane * 2 + 0] = h.x;
    hs[wave][lane * 2 + 1] = h.y;
    __syncthreads();
    if (lane < NCLASS) {
        float acc = 0.f;
        #pragma unroll 8
        for (int k = 0; k < NHID; ++k)
            acc += hs[wave][k] * ldf(W2, (size_t)k * NCLASS + lane, f32);
        HW[(size_t)row * NCLASS + lane] = acc;
    }
}

__global__ __launch_bounds__(256) void spmm2_gather_kernel(
    const int* __restrict__ row_ptr, const int* __restrict__ src_s,
    const float* __restrict__ val_s, const float* __restrict__ HW,
    const void* __restrict__ b2, void* __restrict__ out,
    const int* __restrict__ flag)
{
    const int f32 = *flag;
    const int wave = threadIdx.x >> 6;
    const int lane = threadIdx.x & 63;
    const int row = blockIdx.x * 4 + wave;
    const int beg = row_ptr[row], end = row_ptr[row + 1];
    float acc = 0.f;
    for (int j = beg; j < end; ++j) {
        const int s = src_s[j];
        const float v = val_s[j];
        if (lane < NCLASS) acc += v * HW[(size_t)s * NCLASS + lane];
    }
    const float logit = (lane < NCLASS) ? acc + ldf(b2, lane, f32) : -INFINITY;
    float m = logit;
    #pragma unroll
    for (int o = 32; o >= 1; o >>= 1) m = fmaxf(m, __shfl_xor(m, o));
    float ex = (lane < NCLASS) ? expf(logit - m) : 0.f;
    float sm = ex;
    #pragma unroll
    for (int o = 32; o >= 1; o >>= 1) sm += __shfl_xor(sm, o);
    if (lane < NCLASS) {
        const float r = logit - m - logf(sm);
        const size_t idx = (size_t)row * NCLASS + lane;
        if (f32) ((float*)out)[idx] = r;
        else     ((__hip_bfloat16*)out)[idx] = __float2bfloat16(r);
    }
}

extern "C" void kernel_launch(void* const* d_in, const int* in_sizes, int n_in,
                              void* d_out, int out_size, void* d_ws, size_t ws_size,
                              hipStream_t stream)
{
    const void* x   = d_in[0];
    const void* W1  = d_in[1];
    const void* b1  = d_in[2];
    const void* W2  = d_in[3];
    const void* b2  = d_in[4];
    const int* esrc = (const int*)d_in[5];
    const int* edst = (const int*)d_in[6];
    const void* ev  = d_in[7];

    // workspace layout (floats/ints are both 4 B)
    float* XW      = (float*)d_ws;                         // N*NHID      (25.6 MB)
    float* H1      = XW + (size_t)N_NODES * NHID;          // N*NHID      (25.6 MB)
    float* HW      = H1 + (size_t)N_NODES * NHID;          // N*NCLASS    ( 8.0 MB)
    float* val_s   = HW + (size_t)N_NODES * NCLASS;        // NEDGE       ( 6.4 MB)
    int*   src_s   = (int*)(val_s + NEDGE);                // NEDGE       ( 6.4 MB)
    int*   cnt     = src_s + NEDGE;                        // N           ( 0.2 MB)
    int*   row_ptr = cnt + N_NODES;                        // N+1
    int*   wcur    = row_ptr + N_NODES + 1;                // N
    int*   FLAG    = wcur + N_NODES;                       // 1

    // Split+swizzled W1^T (2 x 128 KB) parked in the HW region: written by
    // w1t_prep, consumed by gemm1_mfma, both strictly before gemm2 writes HW.
    u16* Wt_hi = (u16*)HW;
    u16* Wt_lo = Wt_hi + 65536;

    (void)hipMemsetAsync(cnt, 0, (size_t)N_NODES * sizeof(int), stream);

    detect_kernel<<<1, 256, 0, stream>>>(x, FLAG);

    w1t_prep_kernel<<<256, 256, 0, stream>>>(W1, Wt_hi, Wt_lo, FLAG);

    count_kernel<<<NEDGE / 256, 256, 0, stream>>>(edst, cnt);
    scan_kernel<<<1, 1024, 0, stream>>>(cnt, row_ptr, wcur);
    scatter_kernel<<<NEDGE / 256, 256, 0, stream>>>(esrc, edst, ev, wcur,
                                                    src_s, val_s, FLAG);

    gemm1_mfma_kernel<<<256, 512, 0, stream>>>(x, Wt_hi, Wt_lo, XW, FLAG);

    spmm1_gather_kernel<<<N_NODES / 4, 256, 0, stream>>>(row_ptr, src_s, val_s,
                                                         XW, b1, H1, FLAG);

    gemm2_kernel<<<N_NODES / 4, 256, 0, stream>>>(H1, W2, HW, FLAG);

    spmm2_gather_kernel<<<N_NODES / 4, 256, 0, stream>>>(row_ptr, src_s, val_s,
                                                         HW, b2, d_out, FLAG);
}

// Round 4
// 740.337 us; speedup vs baseline: 1.7265x; 1.1311x over previous
//
#include <hip/hip_runtime.h>
#include <hip/hip_bf16.h>
#include <math.h>

// GCN forward: log_softmax(spmm(relu(spmm(x@W1)+b1) @ W2) + b2)
// Round 7: spmm1_gather was top (161us, FETCH 350MB vs ~38MB ideal, VALUBusy
// 14% -> latency + L2-thrash bound). This round:
//  - XW and HW stored as bf16 (halves gather bytes: 256B / 80B per row)
//  - edge records interleaved as int2{src, val_bits}: 1 scattered 8B store in
//    scatter (was 2x4B), 1 uniform 8B load per edge in the spmm gathers
//  - spmm gathers unrolled x4 with independent accumulators (4 loads in flight)
// gemm1 = split-bf16 MFMA (round 6), epilogue now emits bf16 XW.

#define N_NODES 50000
#define NFEAT   512
#define NHID    128
#define NCLASS  40
#define NEDGE   1600000

typedef unsigned short u16;
typedef unsigned int   u32;
typedef __attribute__((ext_vector_type(8))) short bf16x8;
typedef __attribute__((ext_vector_type(4))) float f32x4;

__device__ __forceinline__ float ldf(const void* p, size_t i, int f32) {
    return f32 ? ((const float*)p)[i]
               : __bfloat162float(((const __hip_bfloat16*)p)[i]);
}

__device__ __forceinline__ u16 f2b(float f) {
    __hip_bfloat16 h = __float2bfloat16(f);
    return *(const u16*)&h;
}
__device__ __forceinline__ float b2f(u32 bits) {
    return __uint_as_float(bits << 16);
}

__global__ __launch_bounds__(256) void detect_kernel(
    const void* __restrict__ x, int* __restrict__ flag)
{
    __shared__ int bad;
    if (threadIdx.x == 0) bad = 0;
    __syncthreads();
    float v = __bfloat162float(((const __hip_bfloat16*)x)[threadIdx.x]);
    if (!(v > -100.f && v < 100.f)) atomicAdd(&bad, 1);
    __syncthreads();
    if (threadIdx.x == 0) *flag = (bad >= 4) ? 1 : 0;   // 1 => fp32
}

// ---- CSR build --------------------------------------------------------------

__global__ __launch_bounds__(256) void count_kernel(
    const int* __restrict__ edst, int* __restrict__ cnt)
{
    const int e = blockIdx.x * 256 + threadIdx.x;
    if (e < NEDGE) atomicAdd(&cnt[edst[e]], 1);
}

__global__ __launch_bounds__(1024) void scan_kernel(
    const int* __restrict__ cnt, int* __restrict__ row_ptr,
    int* __restrict__ wcur)
{
    __shared__ int part[1024];
    const int t = threadIdx.x;
    const int CH = (N_NODES + 1023) / 1024;   // 49
    const int base = t * CH;
    int s = 0;
    for (int i = 0; i < CH; ++i) {
        int idx = base + i;
        if (idx < N_NODES) s += cnt[idx];
    }
    part[t] = s;
    __syncthreads();
    for (int off = 1; off < 1024; off <<= 1) {
        int v = (t >= off) ? part[t - off] : 0;
        __syncthreads();
        part[t] += v;
        __syncthreads();
    }
    int run = part[t] - s;
    for (int i = 0; i < CH; ++i) {
        int idx = base + i;
        if (idx < N_NODES) {
            row_ptr[idx] = run;
            wcur[idx] = run;
            run += cnt[idx];
        }
    }
    if (t == 1023) row_ptr[N_NODES] = part[1023];
}

__global__ __launch_bounds__(256) void scatter_kernel(
    const int* __restrict__ esrc, const int* __restrict__ edst,
    const void* __restrict__ ev, int* __restrict__ wcur,
    int2* __restrict__ erec, const int* __restrict__ flag)
{
    const int f32 = *flag;
    const int e = blockIdx.x * 256 + threadIdx.x;
    if (e >= NEDGE) return;
    const int pos = atomicAdd(&wcur[edst[e]], 1);
    erec[pos] = make_int2(esrc[e], __float_as_int(ldf(ev, e, f32)));
}

// ---- gemm1: split-bf16 MFMA -------------------------------------------------

// W1[512][128] (f32 or bf16) -> Wt_hi/Wt_lo, swizzled per K-quarter:
//   Wt[q*16384 + c*128 + ((k&127) ^ ((c&7)<<3))] = split(W1[k][c]), q = k>>7
__global__ __launch_bounds__(256) void w1t_prep_kernel(
    const void* __restrict__ W1, u16* __restrict__ Wt_hi,
    u16* __restrict__ Wt_lo, const int* __restrict__ flag)
{
    const int f32 = *flag;
    const int e = blockIdx.x * 256 + threadIdx.x;   // grid 256 -> 65536 elems
    const int k = e >> 7, c = e & 127;
    const int q = k >> 7, kq = k & 127;
    const float v = ldf(W1, e, f32);
    __hip_bfloat16 h = __float2bfloat16(v);
    __hip_bfloat16 l = __float2bfloat16(v - __bfloat162float(h));
    const int idx = q * 16384 + c * 128 + (kq ^ ((c & 7) << 3));
    Wt_hi[idx] = *(const u16*)&h;
    Wt_lo[idx] = *(const u16*)&l;
}

__device__ __forceinline__ void async16(const u16* g, u16* l) {
    __builtin_amdgcn_global_load_lds(
        (const __attribute__((address_space(1))) void*)g,
        (__attribute__((address_space(3))) void*)l, 16, 0, 0);
}

__device__ __forceinline__ void split8(const float* p, bf16x8& hi, bf16x8& lo) {
    float t[8];
    *(float4*)&t[0] = *(const float4*)p;
    *(float4*)&t[4] = *(const float4*)(p + 4);
    #pragma unroll
    for (int j = 0; j < 8; ++j) {
        __hip_bfloat16 h = __float2bfloat16(t[j]);
        float r = t[j] - __bfloat162float(h);
        __hip_bfloat16 l = __float2bfloat16(r);
        hi[j] = *(const short*)&h;
        lo[j] = *(const short*)&l;
    }
}

// 256 blocks x 512 threads (8 waves). wave = 32 rows (2 x 16-row tiles),
// all 128 cols. chunk = blockIdx + 256*wave covers ceil(50000/32)=1563 chunks.
__global__ __launch_bounds__(512) void gemm1_mfma_kernel(
    const void* __restrict__ x, const u16* __restrict__ Wt_hi,
    const u16* __restrict__ Wt_lo, u16* __restrict__ XW,
    const int* __restrict__ flag)
{
    __shared__ u16 whi[16384];             // 32 KB: K-quarter of W_hi^T (swz)
    __shared__ u16 wlo[16384];             // 32 KB: K-quarter of W_lo^T (swz)
    const int f32  = *flag;
    const int tid  = threadIdx.x;
    const int wave = tid >> 6;
    const int lane = tid & 63;
    const int g    = lane >> 4;            // k-subgroup 0..3
    const int r16  = lane & 15;
    const int chunk = blockIdx.x + 256 * wave;
    const long row0 = (long)chunk * 32;
    const int  v0 = (row0 < N_NODES);          // 50000 = 32*1562 + 16
    const int  v1 = (row0 + 16 < N_NODES);
    const int  swz = (r16 & 7) << 3;
    const float* xf = (const float*)x;
    const u16*   xb = (const u16*)x;

    f32x4 acc0[8], acc1[8];
    #pragma unroll
    for (int c = 0; c < 8; ++c) {
        acc0[c] = (f32x4){0.f, 0.f, 0.f, 0.f};
        acc1[c] = (f32x4){0.f, 0.f, 0.f, 0.f};
    }

    for (int q = 0; q < 4; ++q) {
        if (q) __syncthreads();            // prev-quarter reads done
        #pragma unroll
        for (int s = 0; s < 4; ++s) {
            const int seg = wave + s * 8;  // 32 segments x 512 u16 (1 KB)
            async16(Wt_hi + q * 16384 + seg * 512 + lane * 8, &whi[seg * 512]);
            async16(Wt_lo + q * 16384 + seg * 512 + lane * 8, &wlo[seg * 512]);
        }
        __syncthreads();                   // drains vmcnt before ds_read

        if (v0) {
            #pragma unroll
            for (int tl = 0; tl < 4; ++tl) {
                const int kq = tl * 32 + g * 8;          // k within quarter
                const size_t kO = (size_t)q * 128 + kq;  // k within 512
                bf16x8 a0h = {0,0,0,0,0,0,0,0}, a0l = {0,0,0,0,0,0,0,0};
                bf16x8 a1h = {0,0,0,0,0,0,0,0}, a1l = {0,0,0,0,0,0,0,0};
                if (f32) {
                    split8(xf + (size_t)(row0 + r16) * NFEAT + kO, a0h, a0l);
                    if (v1)
                        split8(xf + (size_t)(row0 + 16 + r16) * NFEAT + kO,
                               a1h, a1l);
                } else {
                    a0h = *(const bf16x8*)(xb + (size_t)(row0 + r16) * NFEAT + kO);
                    if (v1)
                        a1h = *(const bf16x8*)
                            (xb + (size_t)(row0 + 16 + r16) * NFEAT + kO);
                }
                const int kb = kq ^ swz;
                #pragma unroll
                for (int c = 0; c < 8; ++c) {
                    const bf16x8 bh = *(const bf16x8*)&whi[(c * 16 + r16) * 128 + kb];
                    acc0[c] = __builtin_amdgcn_mfma_f32_16x16x32_bf16(
                        a0h, bh, acc0[c], 0, 0, 0);
                    acc1[c] = __builtin_amdgcn_mfma_f32_16x16x32_bf16(
                        a1h, bh, acc1[c], 0, 0, 0);
                    if (f32) {
                        const bf16x8 bl = *(const bf16x8*)&wlo[(c * 16 + r16) * 128 + kb];
                        acc0[c] = __builtin_amdgcn_mfma_f32_16x16x32_bf16(
                            a0l, bh, acc0[c], 0, 0, 0);
                        acc0[c] = __builtin_amdgcn_mfma_f32_16x16x32_bf16(
                            a0h, bl, acc0[c], 0, 0, 0);
                        acc1[c] = __builtin_amdgcn_mfma_f32_16x16x32_bf16(
                            a1l, bh, acc1[c], 0, 0, 0);
                        acc1[c] = __builtin_amdgcn_mfma_f32_16x16x32_bf16(
                            a1h, bl, acc1[c], 0, 0, 0);
                    }
                }
            }
        }
    }

    // C/D layout (m89-verified): col = lane&15, row = (lane>>4)*4 + reg
    if (v0) {
        #pragma unroll
        for (int c = 0; c < 8; ++c)
            #pragma unroll
            for (int r = 0; r < 4; ++r)
                XW[(size_t)(row0 + g * 4 + r) * NHID + c * 16 + r16] =
                    f2b(acc0[c][r]);
    }
    if (v1) {
        #pragma unroll
        for (int c = 0; c < 8; ++c)
            #pragma unroll
            for (int r = 0; r < 4; ++r)
                XW[(size_t)(row0 + 16 + g * 4 + r) * NHID + c * 16 + r16] =
                    f2b(acc1[c][r]);
    }
}

// ---- sparse + tail compute --------------------------------------------------

// one wave per dst row; lane holds 2 feats (one u32 = 2 bf16); unroll x4
__global__ __launch_bounds__(256) void spmm1_gather_kernel(
    const int* __restrict__ row_ptr, const int2* __restrict__ erec,
    const u16* __restrict__ XW, const void* __restrict__ b1,
    float* __restrict__ H1, const int* __restrict__ flag)
{
    const int f32 = *flag;
    const int wave = threadIdx.x >> 6;
    const int lane = threadIdx.x & 63;
    const int row = blockIdx.x * 4 + wave;
    const int beg = row_ptr[row], end = row_ptr[row + 1];
    const u32* XWu = (const u32*)XW;       // row stride 64 u32

    float2 acc[4];
    #pragma unroll
    for (int u = 0; u < 4; ++u) acc[u] = (float2){0.f, 0.f};

    int j = beg;
    const int n4 = beg + ((end - beg) & ~3);
    for (; j < n4; j += 4) {
        #pragma unroll
        for (int u = 0; u < 4; ++u) {
            const int2 e = erec[j + u];
            const u32 p = XWu[(size_t)e.x * 64 + lane];
            const float v = __int_as_float(e.y);
            acc[u].x += v * b2f(p & 0xffffu);
            acc[u].y += v * b2f(p >> 16);
        }
    }
    for (; j < end; ++j) {
        const int2 e = erec[j];
        const u32 p = XWu[(size_t)e.x * 64 + lane];
        const float v = __int_as_float(e.y);
        acc[0].x += v * b2f(p & 0xffffu);
        acc[0].y += v * b2f(p >> 16);
    }
    float ax = (acc[0].x + acc[1].x) + (acc[2].x + acc[3].x);
    float ay = (acc[0].y + acc[1].y) + (acc[2].y + acc[3].y);
    ax = fmaxf(ax + ldf(b1, lane * 2 + 0, f32), 0.f);
    ay = fmaxf(ay + ldf(b1, lane * 2 + 1, f32), 0.f);
    ((float2*)H1)[(size_t)row * 64 + lane] = (float2){ax, ay};
}

// 4 rows/block (wave per row): HW = H1 @ W2, stored bf16
__global__ __launch_bounds__(256) void gemm2_kernel(
    const float* __restrict__ H1,
    const void* __restrict__ W2,
    u16* __restrict__ HW,
    const int* __restrict__ flag)
{
    __shared__ float hs[4][NHID];
    const int f32 = *flag;
    const int wave = threadIdx.x >> 6;
    const int lane = threadIdx.x & 63;
    const int row = blockIdx.x * 4 + wave;
    const float2 h = ((const float2*)H1)[(size_t)row * 64 + lane];
    hs[wave][lane * 2 + 0] = h.x;
    hs[wave][lane * 2 + 1] = h.y;
    __syncthreads();
    if (lane < NCLASS) {
        float acc = 0.f;
        #pragma unroll 8
        for (int k = 0; k < NHID; ++k)
            acc += hs[wave][k] * ldf(W2, (size_t)k * NCLASS + lane, f32);
        HW[(size_t)row * NCLASS + lane] = f2b(acc);
    }
}

// one wave per dst row; unroll x4; fused +b2 and log_softmax
__global__ __launch_bounds__(256) void spmm2_gather_kernel(
    const int* __restrict__ row_ptr, const int2* __restrict__ erec,
    const u16* __restrict__ HW, const void* __restrict__ b2,
    void* __restrict__ out, const int* __restrict__ flag)
{
    const int f32 = *flag;
    const int wave = threadIdx.x >> 6;
    const int lane = threadIdx.x & 63;
    const int row = blockIdx.x * 4 + wave;
    const int beg = row_ptr[row], end = row_ptr[row + 1];

    float acc[4];
    #pragma unroll
    for (int u = 0; u < 4; ++u) acc[u] = 0.f;

    int j = beg;
    const int n4 = beg + ((end - beg) & ~3);
    for (; j < n4; j += 4) {
        #pragma unroll
        for (int u = 0; u < 4; ++u) {
            const int2 e = erec[j + u];
            if (lane < NCLASS)
                acc[u] += __int_as_float(e.y) *
                          b2f((u32)HW[(size_t)e.x * NCLASS + lane]);
        }
    }
    for (; j < end; ++j) {
        const int2 e = erec[j];
        if (lane < NCLASS)
            acc[0] += __int_as_float(e.y) *
                      b2f((u32)HW[(size_t)e.x * NCLASS + lane]);
    }
    const float a = (acc[0] + acc[1]) + (acc[2] + acc[3]);

    const float logit = (lane < NCLASS) ? a + ldf(b2, lane, f32) : -INFINITY;
    float m = logit;
    #pragma unroll
    for (int o = 32; o >= 1; o >>= 1) m = fmaxf(m, __shfl_xor(m, o));
    float ex = (lane < NCLASS) ? expf(logit - m) : 0.f;
    float sm = ex;
    #pragma unroll
    for (int o = 32; o >= 1; o >>= 1) sm += __shfl_xor(sm, o);
    if (lane < NCLASS) {
        const float r = logit - m - logf(sm);
        const size_t idx = (size_t)row * NCLASS + lane;
        if (f32) ((float*)out)[idx] = r;
        else     ((__hip_bfloat16*)out)[idx] = __float2bfloat16(r);
    }
}

extern "C" void kernel_launch(void* const* d_in, const int* in_sizes, int n_in,
                              void* d_out, int out_size, void* d_ws, size_t ws_size,
                              hipStream_t stream)
{
    const void* x   = d_in[0];
    const void* W1  = d_in[1];
    const void* b1  = d_in[2];
    const void* W2  = d_in[3];
    const void* b2  = d_in[4];
    const int* esrc = (const int*)d_in[5];
    const int* edst = (const int*)d_in[6];
    const void* ev  = d_in[7];

    // workspace layout (region sizes kept from round 6; XW/HW now half-used)
    u16*   XW      = (u16*)d_ws;                           // bf16 N*NHID
    float* H1      = (float*)d_ws + (size_t)N_NODES * NHID; // f32 N*NHID
    u16*   HW      = (u16*)((float*)d_ws + 2 * (size_t)N_NODES * NHID);
    float* region  = (float*)d_ws + 2 * (size_t)N_NODES * NHID
                                  + (size_t)N_NODES * NCLASS;
    int2*  erec    = (int2*)region;                        // NEDGE int2 (12.8MB)
    int*   cnt     = (int*)(erec + NEDGE);                 // N
    int*   row_ptr = cnt + N_NODES;                        // N+1
    int*   wcur    = row_ptr + N_NODES + 1;                // N
    int*   FLAG    = wcur + N_NODES;                       // 1

    // Split+swizzled W1^T (2 x 128 KB) parked in the HW region: written by
    // w1t_prep, consumed by gemm1_mfma, both strictly before gemm2 writes HW.
    u16* Wt_hi = (u16*)HW;
    u16* Wt_lo = Wt_hi + 65536;

    (void)hipMemsetAsync(cnt, 0, (size_t)N_NODES * sizeof(int), stream);

    detect_kernel<<<1, 256, 0, stream>>>(x, FLAG);

    w1t_prep_kernel<<<256, 256, 0, stream>>>(W1, Wt_hi, Wt_lo, FLAG);

    count_kernel<<<NEDGE / 256, 256, 0, stream>>>(edst, cnt);
    scan_kernel<<<1, 1024, 0, stream>>>(cnt, row_ptr, wcur);
    scatter_kernel<<<NEDGE / 256, 256, 0, stream>>>(esrc, edst, ev, wcur,
                                                    erec, FLAG);

    gemm1_mfma_kernel<<<256, 512, 0, stream>>>(x, Wt_hi, Wt_lo, XW, FLAG);

    spmm1_gather_kernel<<<N_NODES / 4, 256, 0, stream>>>(row_ptr, erec,
                                                         XW, b1, H1, FLAG);

    gemm2_kernel<<<N_NODES / 4, 256, 0, stream>>>(H1, W2, HW, FLAG);

    spmm2_gather_kernel<<<N_NODES / 4, 256, 0, stream>>>(row_ptr, erec,
                                                         HW, b2, d_out, FLAG);
}

// Round 5
// 709.333 us; speedup vs baseline: 1.8020x; 1.0437x over previous
//
#include <hip/hip_runtime.h>
#include <hip/hip_bf16.h>
#include <math.h>

// GCN forward: log_softmax(spmm(relu(spmm(x@W1)+b1) @ W2) + b2)
// Round 8: scatter_kernel wrote 101MB for a 12.8MB buffer (8B random stores,
// cross-XCD partial-line writebacks). Replaced with two-pass binned scatter:
//   binA: 391 buckets (128 dst rows each); per-block LDS histogram + one
//         global atomicAdd per bucket reserves a block-exclusive run in temp;
//         runs are written contiguously -> single-XCD lines, amp ~1.2x.
//   binB: one block per bucket; reads its run sequentially, places records at
//         exact CSR positions (wcur atomics) inside a 32KB window -> L2-local.
// Also: spmm gathers unrolled x8; HW padded to stride 64 (line-aligned rows).
// gemm1 = split-bf16 MFMA (round 6); XW/HW bf16 (round 7).

#define N_NODES 50000
#define NFEAT   512
#define NHID    128
#define NCLASS  40
#define NEDGE   1600000
#define NBUCK   391              // ceil(50000/128)

typedef unsigned short u16;
typedef unsigned int   u32;
typedef __attribute__((ext_vector_type(8))) short bf16x8;
typedef __attribute__((ext_vector_type(4))) float f32x4;

__device__ __forceinline__ float ldf(const void* p, size_t i, int f32) {
    return f32 ? ((const float*)p)[i]
               : __bfloat162float(((const __hip_bfloat16*)p)[i]);
}

__device__ __forceinline__ u16 f2b(float f) {
    __hip_bfloat16 h = __float2bfloat16(f);
    return *(const u16*)&h;
}
__device__ __forceinline__ float b2f(u32 bits) {
    return __uint_as_float(bits << 16);
}

__global__ __launch_bounds__(256) void detect_kernel(
    const void* __restrict__ x, int* __restrict__ flag)
{
    __shared__ int bad;
    if (threadIdx.x == 0) bad = 0;
    __syncthreads();
    float v = __bfloat162float(((const __hip_bfloat16*)x)[threadIdx.x]);
    if (!(v > -100.f && v < 100.f)) atomicAdd(&bad, 1);
    __syncthreads();
    if (threadIdx.x == 0) *flag = (bad >= 4) ? 1 : 0;   // 1 => fp32
}

// ---- CSR build --------------------------------------------------------------

__global__ __launch_bounds__(256) void count_kernel(
    const int* __restrict__ edst, int* __restrict__ cnt)
{
    const int e = blockIdx.x * 256 + threadIdx.x;
    if (e < NEDGE) atomicAdd(&cnt[edst[e]], 1);
}

__global__ __launch_bounds__(1024) void scan_kernel(
    const int* __restrict__ cnt, int* __restrict__ row_ptr,
    int* __restrict__ wcur)
{
    __shared__ int part[1024];
    const int t = threadIdx.x;
    const int CH = (N_NODES + 1023) / 1024;   // 49
    const int base = t * CH;
    int s = 0;
    for (int i = 0; i < CH; ++i) {
        int idx = base + i;
        if (idx < N_NODES) s += cnt[idx];
    }
    part[t] = s;
    __syncthreads();
    for (int off = 1; off < 1024; off <<= 1) {
        int v = (t >= off) ? part[t - off] : 0;
        __syncthreads();
        part[t] += v;
        __syncthreads();
    }
    int run = part[t] - s;
    for (int i = 0; i < CH; ++i) {
        int idx = base + i;
        if (idx < N_NODES) {
            row_ptr[idx] = run;
            wcur[idx] = run;
            run += cnt[idx];
        }
    }
    if (t == 1023) row_ptr[N_NODES] = part[1023];
}

// bucket cursors: bcur[b] = row_ptr[b*128]
__global__ __launch_bounds__(512) void binit_kernel(
    const int* __restrict__ row_ptr, int* __restrict__ bcur)
{
    const int t = threadIdx.x;
    if (t < NBUCK) bcur[t] = row_ptr[t * 128];
}

// Pass A: bin edges into 391 buckets; block-exclusive contiguous runs in temp.
// record: x = src | (dst&127)<<16  (src<65536, 7-bit row-in-bucket), y = val
__global__ __launch_bounds__(512) void binA_kernel(
    const int* __restrict__ esrc, const int* __restrict__ edst,
    const void* __restrict__ ev, int* __restrict__ bcur,
    int2* __restrict__ temp, const int* __restrict__ flag)
{
    __shared__ int hist[NBUCK], gbase[NBUCK], loff[NBUCK];
    const int f32 = *flag;
    const int tid = threadIdx.x;
    const int e0  = blockIdx.x * 8192 + tid;

    if (tid < NBUCK) hist[tid] = 0;
    __syncthreads();

    int dsts[16];
    #pragma unroll
    for (int i = 0; i < 16; ++i) {
        const int e = e0 + i * 512;
        dsts[i] = (e < NEDGE) ? edst[e] : -1;
        if (dsts[i] >= 0) atomicAdd(&hist[dsts[i] >> 7], 1);
    }
    __syncthreads();

    if (tid < NBUCK) {
        loff[tid]  = 0;
        gbase[tid] = hist[tid] ? atomicAdd(&bcur[tid], hist[tid]) : 0;
    }
    __syncthreads();

    #pragma unroll
    for (int i = 0; i < 16; ++i) {
        if (dsts[i] >= 0) {
            const int e = e0 + i * 512;
            const int b = dsts[i] >> 7;
            const int o = atomicAdd(&loff[b], 1);
            temp[gbase[b] + o] =
                make_int2(esrc[e] | ((dsts[i] & 127) << 16),
                          __float_as_int(ldf(ev, e, f32)));
        }
    }
}

// Pass B: one block per bucket; exact CSR placement inside a 32KB window.
__global__ __launch_bounds__(256) void binB_kernel(
    const int2* __restrict__ temp, const int* __restrict__ row_ptr,
    int* __restrict__ wcur, int2* __restrict__ erec)
{
    const int b = blockIdx.x;
    const int s = row_ptr[b * 128];
    const int eidx = (b + 1) * 128;
    const int en = row_ptr[eidx > N_NODES ? N_NODES : eidx];
    for (int j = s + threadIdx.x; j < en; j += 256) {
        const int2 r = temp[j];
        const int dst = (b << 7) + ((r.x >> 16) & 127);
        const int pos = atomicAdd(&wcur[dst], 1);
        erec[pos] = make_int2(r.x & 0xFFFF, r.y);
    }
}

// ---- gemm1: split-bf16 MFMA -------------------------------------------------

// W1[512][128] (f32 or bf16) -> Wt_hi/Wt_lo, swizzled per K-quarter:
//   Wt[q*16384 + c*128 + ((k&127) ^ ((c&7)<<3))] = split(W1[k][c]), q = k>>7
__global__ __launch_bounds__(256) void w1t_prep_kernel(
    const void* __restrict__ W1, u16* __restrict__ Wt_hi,
    u16* __restrict__ Wt_lo, const int* __restrict__ flag)
{
    const int f32 = *flag;
    const int e = blockIdx.x * 256 + threadIdx.x;   // grid 256 -> 65536 elems
    const int k = e >> 7, c = e & 127;
    const int q = k >> 7, kq = k & 127;
    const float v = ldf(W1, e, f32);
    __hip_bfloat16 h = __float2bfloat16(v);
    __hip_bfloat16 l = __float2bfloat16(v - __bfloat162float(h));
    const int idx = q * 16384 + c * 128 + (kq ^ ((c & 7) << 3));
    Wt_hi[idx] = *(const u16*)&h;
    Wt_lo[idx] = *(const u16*)&l;
}

__device__ __forceinline__ void async16(const u16* g, u16* l) {
    __builtin_amdgcn_global_load_lds(
        (const __attribute__((address_space(1))) void*)g,
        (__attribute__((address_space(3))) void*)l, 16, 0, 0);
}

__device__ __forceinline__ void split8(const float* p, bf16x8& hi, bf16x8& lo) {
    float t[8];
    *(float4*)&t[0] = *(const float4*)p;
    *(float4*)&t[4] = *(const float4*)(p + 4);
    #pragma unroll
    for (int j = 0; j < 8; ++j) {
        __hip_bfloat16 h = __float2bfloat16(t[j]);
        float r = t[j] - __bfloat162float(h);
        __hip_bfloat16 l = __float2bfloat16(r);
        hi[j] = *(const short*)&h;
        lo[j] = *(const short*)&l;
    }
}

// 256 blocks x 512 threads (8 waves). wave = 32 rows (2 x 16-row tiles),
// all 128 cols. chunk = blockIdx + 256*wave covers ceil(50000/32)=1563 chunks.
__global__ __launch_bounds__(512) void gemm1_mfma_kernel(
    const void* __restrict__ x, const u16* __restrict__ Wt_hi,
    const u16* __restrict__ Wt_lo, u16* __restrict__ XW,
    const int* __restrict__ flag)
{
    __shared__ u16 whi[16384];             // 32 KB: K-quarter of W_hi^T (swz)
    __shared__ u16 wlo[16384];             // 32 KB: K-quarter of W_lo^T (swz)
    const int f32  = *flag;
    const int tid  = threadIdx.x;
    const int wave = tid >> 6;
    const int lane = tid & 63;
    const int g    = lane >> 4;            // k-subgroup 0..3
    const int r16  = lane & 15;
    const int chunk = blockIdx.x + 256 * wave;
    const long row0 = (long)chunk * 32;
    const int  v0 = (row0 < N_NODES);          // 50000 = 32*1562 + 16
    const int  v1 = (row0 + 16 < N_NODES);
    const int  swz = (r16 & 7) << 3;
    const float* xf = (const float*)x;
    const u16*   xb = (const u16*)x;

    f32x4 acc0[8], acc1[8];
    #pragma unroll
    for (int c = 0; c < 8; ++c) {
        acc0[c] = (f32x4){0.f, 0.f, 0.f, 0.f};
        acc1[c] = (f32x4){0.f, 0.f, 0.f, 0.f};
    }

    for (int q = 0; q < 4; ++q) {
        if (q) __syncthreads();            // prev-quarter reads done
        #pragma unroll
        for (int s = 0; s < 4; ++s) {
            const int seg = wave + s * 8;  // 32 segments x 512 u16 (1 KB)
            async16(Wt_hi + q * 16384 + seg * 512 + lane * 8, &whi[seg * 512]);
            async16(Wt_lo + q * 16384 + seg * 512 + lane * 8, &wlo[seg * 512]);
        }
        __syncthreads();                   // drains vmcnt before ds_read

        if (v0) {
            #pragma unroll
            for (int tl = 0; tl < 4; ++tl) {
                const int kq = tl * 32 + g * 8;          // k within quarter
                const size_t kO = (size_t)q * 128 + kq;  // k within 512
                bf16x8 a0h = {0,0,0,0,0,0,0,0}, a0l = {0,0,0,0,0,0,0,0};
                bf16x8 a1h = {0,0,0,0,0,0,0,0}, a1l = {0,0,0,0,0,0,0,0};
                if (f32) {
                    split8(xf + (size_t)(row0 + r16) * NFEAT + kO, a0h, a0l);
                    if (v1)
                        split8(xf + (size_t)(row0 + 16 + r16) * NFEAT + kO,
                               a1h, a1l);
                } else {
                    a0h = *(const bf16x8*)(xb + (size_t)(row0 + r16) * NFEAT + kO);
                    if (v1)
                        a1h = *(const bf16x8*)
                            (xb + (size_t)(row0 + 16 + r16) * NFEAT + kO);
                }
                const int kb = kq ^ swz;
                #pragma unroll
                for (int c = 0; c < 8; ++c) {
                    const bf16x8 bh = *(const bf16x8*)&whi[(c * 16 + r16) * 128 + kb];
                    acc0[c] = __builtin_amdgcn_mfma_f32_16x16x32_bf16(
                        a0h, bh, acc0[c], 0, 0, 0);
                    acc1[c] = __builtin_amdgcn_mfma_f32_16x16x32_bf16(
                        a1h, bh, acc1[c], 0, 0, 0);
                    if (f32) {
                        const bf16x8 bl = *(const bf16x8*)&wlo[(c * 16 + r16) * 128 + kb];
                        acc0[c] = __builtin_amdgcn_mfma_f32_16x16x32_bf16(
                            a0l, bh, acc0[c], 0, 0, 0);
                        acc0[c] = __builtin_amdgcn_mfma_f32_16x16x32_bf16(
                            a0h, bl, acc0[c], 0, 0, 0);
                        acc1[c] = __builtin_amdgcn_mfma_f32_16x16x32_bf16(
                            a1l, bh, acc1[c], 0, 0, 0);
                        acc1[c] = __builtin_amdgcn_mfma_f32_16x16x32_bf16(
                            a1h, bl, acc1[c], 0, 0, 0);
                    }
                }
            }
        }
    }

    // C/D layout (m89-verified): col = lane&15, row = (lane>>4)*4 + reg
    if (v0) {
        #pragma unroll
        for (int c = 0; c < 8; ++c)
            #pragma unroll
            for (int r = 0; r < 4; ++r)
                XW[(size_t)(row0 + g * 4 + r) * NHID + c * 16 + r16] =
                    f2b(acc0[c][r]);
    }
    if (v1) {
        #pragma unroll
        for (int c = 0; c < 8; ++c)
            #pragma unroll
            for (int r = 0; r < 4; ++r)
                XW[(size_t)(row0 + 16 + g * 4 + r) * NHID + c * 16 + r16] =
                    f2b(acc1[c][r]);
    }
}

// ---- sparse + tail compute --------------------------------------------------

// one wave per dst row; lane holds 2 feats (one u32 = 2 bf16); unroll x8
__global__ __launch_bounds__(256) void spmm1_gather_kernel(
    const int* __restrict__ row_ptr, const int2* __restrict__ erec,
    const u16* __restrict__ XW, const void* __restrict__ b1,
    float* __restrict__ H1, const int* __restrict__ flag)
{
    const int f32 = *flag;
    const int wave = threadIdx.x >> 6;
    const int lane = threadIdx.x & 63;
    const int row = blockIdx.x * 4 + wave;
    const int beg = row_ptr[row], end = row_ptr[row + 1];
    const u32* XWu = (const u32*)XW;       // row stride 64 u32

    float2 acc[8];
    #pragma unroll
    for (int u = 0; u < 8; ++u) acc[u] = (float2){0.f, 0.f};

    int j = beg;
    const int n8 = beg + ((end - beg) & ~7);
    for (; j < n8; j += 8) {
        #pragma unroll
        for (int u = 0; u < 8; ++u) {
            const int2 e = erec[j + u];
            const u32 p = XWu[((size_t)e.x << 6) + lane];
            const float v = __int_as_float(e.y);
            acc[u].x += v * b2f(p & 0xffffu);
            acc[u].y += v * b2f(p >> 16);
        }
    }
    for (; j < end; ++j) {
        const int2 e = erec[j];
        const u32 p = XWu[((size_t)e.x << 6) + lane];
        const float v = __int_as_float(e.y);
        acc[0].x += v * b2f(p & 0xffffu);
        acc[0].y += v * b2f(p >> 16);
    }
    float ax = ((acc[0].x + acc[1].x) + (acc[2].x + acc[3].x)) +
               ((acc[4].x + acc[5].x) + (acc[6].x + acc[7].x));
    float ay = ((acc[0].y + acc[1].y) + (acc[2].y + acc[3].y)) +
               ((acc[4].y + acc[5].y) + (acc[6].y + acc[7].y));
    ax = fmaxf(ax + ldf(b1, lane * 2 + 0, f32), 0.f);
    ay = fmaxf(ay + ldf(b1, lane * 2 + 1, f32), 0.f);
    ((float2*)H1)[(size_t)row * 64 + lane] = (float2){ax, ay};
}

// 4 rows/block (wave per row): HW = H1 @ W2, stored bf16, stride 64 (padded)
__global__ __launch_bounds__(256) void gemm2_kernel(
    const float* __restrict__ H1,
    const void* __restrict__ W2,
    u16* __restrict__ HW,
    const int* __restrict__ flag)
{
    __shared__ float hs[4][NHID];
    const int f32 = *flag;
    const int wave = threadIdx.x >> 6;
    const int lane = threadIdx.x & 63;
    const int row = blockIdx.x * 4 + wave;
    const float2 h = ((const float2*)H1)[(size_t)row * 64 + lane];
    hs[wave][lane * 2 + 0] = h.x;
    hs[wave][lane * 2 + 1] = h.y;
    __syncthreads();
    if (lane < NCLASS) {
        float acc = 0.f;
        #pragma unroll 8
        for (int k = 0; k < NHID; ++k)
            acc += hs[wave][k] * ldf(W2, (size_t)k * NCLASS + lane, f32);
        HW[((size_t)row << 6) + lane] = f2b(acc);
    }
}

// one wave per dst row; unroll x8; fused +b2 and log_softmax
__global__ __launch_bounds__(256) void spmm2_gather_kernel(
    const int* __restrict__ row_ptr, const int2* __restrict__ erec,
    const u16* __restrict__ HW, const void* __restrict__ b2,
    void* __restrict__ out, const int* __restrict__ flag)
{
    const int f32 = *flag;
    const int wave = threadIdx.x >> 6;
    const int lane = threadIdx.x & 63;
    const int row = blockIdx.x * 4 + wave;
    const int beg = row_ptr[row], end = row_ptr[row + 1];

    float acc[8];
    #pragma unroll
    for (int u = 0; u < 8; ++u) acc[u] = 0.f;

    int j = beg;
    const int n8 = beg + ((end - beg) & ~7);
    for (; j < n8; j += 8) {
        #pragma unroll
        for (int u = 0; u < 8; ++u) {
            const int2 e = erec[j + u];
            if (lane < NCLASS)
                acc[u] += __int_as_float(e.y) *
                          b2f((u32)HW[((size_t)e.x << 6) + lane]);
        }
    }
    for (; j < end; ++j) {
        const int2 e = erec[j];
        if (lane < NCLASS)
            acc[0] += __int_as_float(e.y) *
                      b2f((u32)HW[((size_t)e.x << 6) + lane]);
    }
    const float a = ((acc[0] + acc[1]) + (acc[2] + acc[3])) +
                    ((acc[4] + acc[5]) + (acc[6] + acc[7]));

    const float logit = (lane < NCLASS) ? a + ldf(b2, lane, f32) : -INFINITY;
    float m = logit;
    #pragma unroll
    for (int o = 32; o >= 1; o >>= 1) m = fmaxf(m, __shfl_xor(m, o));
    float ex = (lane < NCLASS) ? expf(logit - m) : 0.f;
    float sm = ex;
    #pragma unroll
    for (int o = 32; o >= 1; o >>= 1) sm += __shfl_xor(sm, o);
    if (lane < NCLASS) {
        const float r = logit - m - logf(sm);
        const size_t idx = (size_t)row * NCLASS + lane;
        if (f32) ((float*)out)[idx] = r;
        else     ((__hip_bfloat16*)out)[idx] = __float2bfloat16(r);
    }
}

extern "C" void kernel_launch(void* const* d_in, const int* in_sizes, int n_in,
                              void* d_out, int out_size, void* d_ws, size_t ws_size,
                              hipStream_t stream)
{
    const void* x   = d_in[0];
    const void* W1  = d_in[1];
    const void* b1  = d_in[2];
    const void* W2  = d_in[3];
    const void* b2  = d_in[4];
    const int* esrc = (const int*)d_in[5];
    const int* edst = (const int*)d_in[6];
    const void* ev  = d_in[7];

    // workspace layout
    u16*   XW      = (u16*)d_ws;                            // bf16 N*NHID (12.8MB)
    int2*  temp    = (int2*)((char*)d_ws + (size_t)N_NODES * NHID * 2); // 12.8MB
    float* H1      = (float*)d_ws + (size_t)N_NODES * NHID; // f32 N*NHID (25.6MB)
    u16*   HW      = (u16*)((float*)d_ws + 2 * (size_t)N_NODES * NHID); // stride 64
    float* region  = (float*)d_ws + 2 * (size_t)N_NODES * NHID
                                  + (size_t)N_NODES * NCLASS;
    int2*  erec    = (int2*)region;                        // NEDGE int2 (12.8MB)
    int*   cnt     = (int*)(erec + NEDGE);                 // N
    int*   row_ptr = cnt + N_NODES;                        // N+1
    int*   wcur    = row_ptr + N_NODES + 1;                // N
    int*   FLAG    = wcur + N_NODES;                       // 1
    int*   bcur    = FLAG + 1;                             // NBUCK

    // Split+swizzled W1^T (2 x 128 KB) parked in the HW region: written by
    // w1t_prep, consumed by gemm1_mfma, both strictly before gemm2 writes HW.
    // (HW padded rows use 6.4MB of the 8MB region, still >256KB headroom at
    //  the start is NOT available -- Wt lives at region start, but gemm2 only
    //  writes HW after gemm1 is done reading Wt, so aliasing is safe.)
    u16* Wt_hi = (u16*)HW;
    u16* Wt_lo = Wt_hi + 65536;

    (void)hipMemsetAsync(cnt, 0, (size_t)N_NODES * sizeof(int), stream);

    detect_kernel<<<1, 256, 0, stream>>>(x, FLAG);

    w1t_prep_kernel<<<256, 256, 0, stream>>>(W1, Wt_hi, Wt_lo, FLAG);

    count_kernel<<<NEDGE / 256, 256, 0, stream>>>(edst, cnt);
    scan_kernel<<<1, 1024, 0, stream>>>(cnt, row_ptr, wcur);
    binit_kernel<<<1, 512, 0, stream>>>(row_ptr, bcur);
    binA_kernel<<<(NEDGE + 8191) / 8192, 512, 0, stream>>>(esrc, edst, ev,
                                                           bcur, temp, FLAG);
    binB_kernel<<<NBUCK, 256, 0, stream>>>(temp, row_ptr, wcur, erec);

    gemm1_mfma_kernel<<<256, 512, 0, stream>>>(x, Wt_hi, Wt_lo, XW, FLAG);

    spmm1_gather_kernel<<<N_NODES / 4, 256, 0, stream>>>(row_ptr, erec,
                                                         XW, b1, H1, FLAG);

    gemm2_kernel<<<N_NODES / 4, 256, 0, stream>>>(H1, W2, HW, FLAG);

    spmm2_gather_kernel<<<N_NODES / 4, 256, 0, stream>>>(row_ptr, erec,
                                                         HW, b2, d_out, FLAG);
}

// Round 6
// 665.162 us; speedup vs baseline: 1.9216x; 1.0664x over previous
//
#include <hip/hip_runtime.h>
#include <hip/hip_bf16.h>
#include <math.h>

// GCN forward: log_softmax(spmm(relu(spmm(x@W1)+b1) @ W2) + b2)
// Round 9: spmm2 regressed 129->141us with FETCH 36->57.7MB. Post-mortem:
//  (a) stride-64 HW padding grew it 4->6.4MB -> fell out of per-XCD L2;
//  (b) VGPR_Count=12 on both spmm kernels => the compiler collapsed the
//      "unroll x8" into ~2 loads in flight (no MLP).
// Fix: HW back to stride 40 (4.0MB, L2-resident); both spmm gathers use
// explicit three-phase batches (load all erec -> issue all gathers -> FMA)
// in separated loops so the gathers stay in flight (batch 8 for spmm1,
// 16 for spmm2). Everything else unchanged (binned scatter r8, split-bf16
// MFMA gemm1 r6, bf16 XW/HW r7).

#define N_NODES 50000
#define NFEAT   512
#define NHID    128
#define NCLASS  40
#define NEDGE   1600000
#define NBUCK   391              // ceil(50000/128)

typedef unsigned short u16;
typedef unsigned int   u32;
typedef __attribute__((ext_vector_type(8))) short bf16x8;
typedef __attribute__((ext_vector_type(4))) float f32x4;

__device__ __forceinline__ float ldf(const void* p, size_t i, int f32) {
    return f32 ? ((const float*)p)[i]
               : __bfloat162float(((const __hip_bfloat16*)p)[i]);
}

__device__ __forceinline__ u16 f2b(float f) {
    __hip_bfloat16 h = __float2bfloat16(f);
    return *(const u16*)&h;
}
__device__ __forceinline__ float b2f(u32 bits) {
    return __uint_as_float(bits << 16);
}

__global__ __launch_bounds__(256) void detect_kernel(
    const void* __restrict__ x, int* __restrict__ flag)
{
    __shared__ int bad;
    if (threadIdx.x == 0) bad = 0;
    __syncthreads();
    float v = __bfloat162float(((const __hip_bfloat16*)x)[threadIdx.x]);
    if (!(v > -100.f && v < 100.f)) atomicAdd(&bad, 1);
    __syncthreads();
    if (threadIdx.x == 0) *flag = (bad >= 4) ? 1 : 0;   // 1 => fp32
}

// ---- CSR build --------------------------------------------------------------

__global__ __launch_bounds__(256) void count_kernel(
    const int* __restrict__ edst, int* __restrict__ cnt)
{
    const int e = blockIdx.x * 256 + threadIdx.x;
    if (e < NEDGE) atomicAdd(&cnt[edst[e]], 1);
}

__global__ __launch_bounds__(1024) void scan_kernel(
    const int* __restrict__ cnt, int* __restrict__ row_ptr,
    int* __restrict__ wcur)
{
    __shared__ int part[1024];
    const int t = threadIdx.x;
    const int CH = (N_NODES + 1023) / 1024;   // 49
    const int base = t * CH;
    int s = 0;
    for (int i = 0; i < CH; ++i) {
        int idx = base + i;
        if (idx < N_NODES) s += cnt[idx];
    }
    part[t] = s;
    __syncthreads();
    for (int off = 1; off < 1024; off <<= 1) {
        int v = (t >= off) ? part[t - off] : 0;
        __syncthreads();
        part[t] += v;
        __syncthreads();
    }
    int run = part[t] - s;
    for (int i = 0; i < CH; ++i) {
        int idx = base + i;
        if (idx < N_NODES) {
            row_ptr[idx] = run;
            wcur[idx] = run;
            run += cnt[idx];
        }
    }
    if (t == 1023) row_ptr[N_NODES] = part[1023];
}

// bucket cursors: bcur[b] = row_ptr[b*128]
__global__ __launch_bounds__(512) void binit_kernel(
    const int* __restrict__ row_ptr, int* __restrict__ bcur)
{
    const int t = threadIdx.x;
    if (t < NBUCK) bcur[t] = row_ptr[t * 128];
}

// Pass A: bin edges into 391 buckets; block-exclusive contiguous runs in temp.
// record: x = src | (dst&127)<<16  (src<65536, 7-bit row-in-bucket), y = val
__global__ __launch_bounds__(512) void binA_kernel(
    const int* __restrict__ esrc, const int* __restrict__ edst,
    const void* __restrict__ ev, int* __restrict__ bcur,
    int2* __restrict__ temp, const int* __restrict__ flag)
{
    __shared__ int hist[NBUCK], gbase[NBUCK], loff[NBUCK];
    const int f32 = *flag;
    const int tid = threadIdx.x;
    const int e0  = blockIdx.x * 8192 + tid;

    if (tid < NBUCK) hist[tid] = 0;
    __syncthreads();

    int dsts[16];
    #pragma unroll
    for (int i = 0; i < 16; ++i) {
        const int e = e0 + i * 512;
        dsts[i] = (e < NEDGE) ? edst[e] : -1;
        if (dsts[i] >= 0) atomicAdd(&hist[dsts[i] >> 7], 1);
    }
    __syncthreads();

    if (tid < NBUCK) {
        loff[tid]  = 0;
        gbase[tid] = hist[tid] ? atomicAdd(&bcur[tid], hist[tid]) : 0;
    }
    __syncthreads();

    #pragma unroll
    for (int i = 0; i < 16; ++i) {
        if (dsts[i] >= 0) {
            const int e = e0 + i * 512;
            const int b = dsts[i] >> 7;
            const int o = atomicAdd(&loff[b], 1);
            temp[gbase[b] + o] =
                make_int2(esrc[e] | ((dsts[i] & 127) << 16),
                          __float_as_int(ldf(ev, e, f32)));
        }
    }
}

// Pass B: one block per bucket; exact CSR placement inside a 32KB window.
__global__ __launch_bounds__(256) void binB_kernel(
    const int2* __restrict__ temp, const int* __restrict__ row_ptr,
    int* __restrict__ wcur, int2* __restrict__ erec)
{
    const int b = blockIdx.x;
    const int s = row_ptr[b * 128];
    const int eidx = (b + 1) * 128;
    const int en = row_ptr[eidx > N_NODES ? N_NODES : eidx];
    for (int j = s + threadIdx.x; j < en; j += 256) {
        const int2 r = temp[j];
        const int dst = (b << 7) + ((r.x >> 16) & 127);
        const int pos = atomicAdd(&wcur[dst], 1);
        erec[pos] = make_int2(r.x & 0xFFFF, r.y);
    }
}

// ---- gemm1: split-bf16 MFMA -------------------------------------------------

// W1[512][128] (f32 or bf16) -> Wt_hi/Wt_lo, swizzled per K-quarter:
//   Wt[q*16384 + c*128 + ((k&127) ^ ((c&7)<<3))] = split(W1[k][c]), q = k>>7
__global__ __launch_bounds__(256) void w1t_prep_kernel(
    const void* __restrict__ W1, u16* __restrict__ Wt_hi,
    u16* __restrict__ Wt_lo, const int* __restrict__ flag)
{
    const int f32 = *flag;
    const int e = blockIdx.x * 256 + threadIdx.x;   // grid 256 -> 65536 elems
    const int k = e >> 7, c = e & 127;
    const int q = k >> 7, kq = k & 127;
    const float v = ldf(W1, e, f32);
    __hip_bfloat16 h = __float2bfloat16(v);
    __hip_bfloat16 l = __float2bfloat16(v - __bfloat162float(h));
    const int idx = q * 16384 + c * 128 + (kq ^ ((c & 7) << 3));
    Wt_hi[idx] = *(const u16*)&h;
    Wt_lo[idx] = *(const u16*)&l;
}

__device__ __forceinline__ void async16(const u16* g, u16* l) {
    __builtin_amdgcn_global_load_lds(
        (const __attribute__((address_space(1))) void*)g,
        (__attribute__((address_space(3))) void*)l, 16, 0, 0);
}

__device__ __forceinline__ void split8(const float* p, bf16x8& hi, bf16x8& lo) {
    float t[8];
    *(float4*)&t[0] = *(const float4*)p;
    *(float4*)&t[4] = *(const float4*)(p + 4);
    #pragma unroll
    for (int j = 0; j < 8; ++j) {
        __hip_bfloat16 h = __float2bfloat16(t[j]);
        float r = t[j] - __bfloat162float(h);
        __hip_bfloat16 l = __float2bfloat16(r);
        hi[j] = *(const short*)&h;
        lo[j] = *(const short*)&l;
    }
}

// 256 blocks x 512 threads (8 waves). wave = 32 rows (2 x 16-row tiles),
// all 128 cols. chunk = blockIdx + 256*wave covers ceil(50000/32)=1563 chunks.
__global__ __launch_bounds__(512) void gemm1_mfma_kernel(
    const void* __restrict__ x, const u16* __restrict__ Wt_hi,
    const u16* __restrict__ Wt_lo, u16* __restrict__ XW,
    const int* __restrict__ flag)
{
    __shared__ u16 whi[16384];             // 32 KB: K-quarter of W_hi^T (swz)
    __shared__ u16 wlo[16384];             // 32 KB: K-quarter of W_lo^T (swz)
    const int f32  = *flag;
    const int tid  = threadIdx.x;
    const int wave = tid >> 6;
    const int lane = tid & 63;
    const int g    = lane >> 4;            // k-subgroup 0..3
    const int r16  = lane & 15;
    const int chunk = blockIdx.x + 256 * wave;
    const long row0 = (long)chunk * 32;
    const int  v0 = (row0 < N_NODES);          // 50000 = 32*1562 + 16
    const int  v1 = (row0 + 16 < N_NODES);
    const int  swz = (r16 & 7) << 3;
    const float* xf = (const float*)x;
    const u16*   xb = (const u16*)x;

    f32x4 acc0[8], acc1[8];
    #pragma unroll
    for (int c = 0; c < 8; ++c) {
        acc0[c] = (f32x4){0.f, 0.f, 0.f, 0.f};
        acc1[c] = (f32x4){0.f, 0.f, 0.f, 0.f};
    }

    for (int q = 0; q < 4; ++q) {
        if (q) __syncthreads();            // prev-quarter reads done
        #pragma unroll
        for (int s = 0; s < 4; ++s) {
            const int seg = wave + s * 8;  // 32 segments x 512 u16 (1 KB)
            async16(Wt_hi + q * 16384 + seg * 512 + lane * 8, &whi[seg * 512]);
            async16(Wt_lo + q * 16384 + seg * 512 + lane * 8, &wlo[seg * 512]);
        }
        __syncthreads();                   // drains vmcnt before ds_read

        if (v0) {
            #pragma unroll
            for (int tl = 0; tl < 4; ++tl) {
                const int kq = tl * 32 + g * 8;          // k within quarter
                const size_t kO = (size_t)q * 128 + kq;  // k within 512
                bf16x8 a0h = {0,0,0,0,0,0,0,0}, a0l = {0,0,0,0,0,0,0,0};
                bf16x8 a1h = {0,0,0,0,0,0,0,0}, a1l = {0,0,0,0,0,0,0,0};
                if (f32) {
                    split8(xf + (size_t)(row0 + r16) * NFEAT + kO, a0h, a0l);
                    if (v1)
                        split8(xf + (size_t)(row0 + 16 + r16) * NFEAT + kO,
                               a1h, a1l);
                } else {
                    a0h = *(const bf16x8*)(xb + (size_t)(row0 + r16) * NFEAT + kO);
                    if (v1)
                        a1h = *(const bf16x8*)
                            (xb + (size_t)(row0 + 16 + r16) * NFEAT + kO);
                }
                const int kb = kq ^ swz;
                #pragma unroll
                for (int c = 0; c < 8; ++c) {
                    const bf16x8 bh = *(const bf16x8*)&whi[(c * 16 + r16) * 128 + kb];
                    acc0[c] = __builtin_amdgcn_mfma_f32_16x16x32_bf16(
                        a0h, bh, acc0[c], 0, 0, 0);
                    acc1[c] = __builtin_amdgcn_mfma_f32_16x16x32_bf16(
                        a1h, bh, acc1[c], 0, 0, 0);
                    if (f32) {
                        const bf16x8 bl = *(const bf16x8*)&wlo[(c * 16 + r16) * 128 + kb];
                        acc0[c] = __builtin_amdgcn_mfma_f32_16x16x32_bf16(
                            a0l, bh, acc0[c], 0, 0, 0);
                        acc0[c] = __builtin_amdgcn_mfma_f32_16x16x32_bf16(
                            a0h, bl, acc0[c], 0, 0, 0);
                        acc1[c] = __builtin_amdgcn_mfma_f32_16x16x32_bf16(
                            a1l, bh, acc1[c], 0, 0, 0);
                        acc1[c] = __builtin_amdgcn_mfma_f32_16x16x32_bf16(
                            a1h, bl, acc1[c], 0, 0, 0);
                    }
                }
            }
        }
    }

    // C/D layout (m89-verified): col = lane&15, row = (lane>>4)*4 + reg
    if (v0) {
        #pragma unroll
        for (int c = 0; c < 8; ++c)
            #pragma unroll
            for (int r = 0; r < 4; ++r)
                XW[(size_t)(row0 + g * 4 + r) * NHID + c * 16 + r16] =
                    f2b(acc0[c][r]);
    }
    if (v1) {
        #pragma unroll
        for (int c = 0; c < 8; ++c)
            #pragma unroll
            for (int r = 0; r < 4; ++r)
                XW[(size_t)(row0 + 16 + g * 4 + r) * NHID + c * 16 + r16] =
                    f2b(acc1[c][r]);
    }
}

// ---- sparse + tail compute --------------------------------------------------

// one wave per dst row; lane holds 2 feats (one u32 = 2 bf16).
// Three-phase batches of 8: all erec loads -> all gathers -> FMA, in
// separated loops so 8 gathers stay in flight.
__global__ __launch_bounds__(256) void spmm1_gather_kernel(
    const int* __restrict__ row_ptr, const int2* __restrict__ erec,
    const u16* __restrict__ XW, const void* __restrict__ b1,
    float* __restrict__ H1, const int* __restrict__ flag)
{
    const int f32 = *flag;
    const int wave = threadIdx.x >> 6;
    const int lane = threadIdx.x & 63;
    const int row = blockIdx.x * 4 + wave;
    const int beg = row_ptr[row], end = row_ptr[row + 1];
    const u32* XWu = (const u32*)XW;       // row stride 64 u32

    float2 acc[4];
    #pragma unroll
    for (int u = 0; u < 4; ++u) acc[u] = (float2){0.f, 0.f};

    int j = beg;
    for (; j + 8 <= end; j += 8) {
        int2 e[8];
        #pragma unroll
        for (int u = 0; u < 8; ++u) e[u] = erec[j + u];
        u32 p[8];
        #pragma unroll
        for (int u = 0; u < 8; ++u) p[u] = XWu[((size_t)e[u].x << 6) + lane];
        #pragma unroll
        for (int u = 0; u < 8; ++u) {
            const float v = __int_as_float(e[u].y);
            acc[u & 3].x += v * b2f(p[u] & 0xffffu);
            acc[u & 3].y += v * b2f(p[u] >> 16);
        }
    }
    for (; j < end; ++j) {
        const int2 e = erec[j];
        const u32 p = XWu[((size_t)e.x << 6) + lane];
        const float v = __int_as_float(e.y);
        acc[0].x += v * b2f(p & 0xffffu);
        acc[0].y += v * b2f(p >> 16);
    }
    float ax = (acc[0].x + acc[1].x) + (acc[2].x + acc[3].x);
    float ay = (acc[0].y + acc[1].y) + (acc[2].y + acc[3].y);
    ax = fmaxf(ax + ldf(b1, lane * 2 + 0, f32), 0.f);
    ay = fmaxf(ay + ldf(b1, lane * 2 + 1, f32), 0.f);
    ((float2*)H1)[(size_t)row * 64 + lane] = (float2){ax, ay};
}

// 4 rows/block (wave per row): HW = H1 @ W2, stored bf16, stride 40 (4.0 MB)
__global__ __launch_bounds__(256) void gemm2_kernel(
    const float* __restrict__ H1,
    const void* __restrict__ W2,
    u16* __restrict__ HW,
    const int* __restrict__ flag)
{
    __shared__ float hs[4][NHID];
    const int f32 = *flag;
    const int wave = threadIdx.x >> 6;
    const int lane = threadIdx.x & 63;
    const int row = blockIdx.x * 4 + wave;
    const float2 h = ((const float2*)H1)[(size_t)row * 64 + lane];
    hs[wave][lane * 2 + 0] = h.x;
    hs[wave][lane * 2 + 1] = h.y;
    __syncthreads();
    if (lane < NCLASS) {
        float acc = 0.f;
        #pragma unroll 8
        for (int k = 0; k < NHID; ++k)
            acc += hs[wave][k] * ldf(W2, (size_t)k * NCLASS + lane, f32);
        HW[(size_t)row * NCLASS + lane] = f2b(acc);
    }
}

// one wave per dst row; three-phase batches of 16; fused +b2 and log_softmax
__global__ __launch_bounds__(256) void spmm2_gather_kernel(
    const int* __restrict__ row_ptr, const int2* __restrict__ erec,
    const u16* __restrict__ HW, const void* __restrict__ b2,
    void* __restrict__ out, const int* __restrict__ flag)
{
    const int f32 = *flag;
    const int wave = threadIdx.x >> 6;
    const int lane = threadIdx.x & 63;
    const int row = blockIdx.x * 4 + wave;
    const int beg = row_ptr[row], end = row_ptr[row + 1];
    const int cls = (lane < NCLASS);

    float acc[4];
    #pragma unroll
    for (int u = 0; u < 4; ++u) acc[u] = 0.f;

    int j = beg;
    for (; j + 16 <= end; j += 16) {
        int2 e[16];
        #pragma unroll
        for (int u = 0; u < 16; ++u) e[u] = erec[j + u];
        u16 h[16];
        #pragma unroll
        for (int u = 0; u < 16; ++u)
            h[u] = cls ? HW[(size_t)e[u].x * NCLASS + lane] : (u16)0;
        #pragma unroll
        for (int u = 0; u < 16; ++u)
            acc[u & 3] += __int_as_float(e[u].y) * b2f((u32)h[u]);
    }
    for (; j < end; ++j) {
        const int2 e = erec[j];
        if (cls)
            acc[0] += __int_as_float(e.y) *
                      b2f((u32)HW[(size_t)e.x * NCLASS + lane]);
    }
    const float a = (acc[0] + acc[1]) + (acc[2] + acc[3]);

    const float logit = cls ? a + ldf(b2, lane, f32) : -INFINITY;
    float m = logit;
    #pragma unroll
    for (int o = 32; o >= 1; o >>= 1) m = fmaxf(m, __shfl_xor(m, o));
    float ex = cls ? expf(logit - m) : 0.f;
    float sm = ex;
    #pragma unroll
    for (int o = 32; o >= 1; o >>= 1) sm += __shfl_xor(sm, o);
    if (cls) {
        const float r = logit - m - logf(sm);
        const size_t idx = (size_t)row * NCLASS + lane;
        if (f32) ((float*)out)[idx] = r;
        else     ((__hip_bfloat16*)out)[idx] = __float2bfloat16(r);
    }
}

extern "C" void kernel_launch(void* const* d_in, const int* in_sizes, int n_in,
                              void* d_out, int out_size, void* d_ws, size_t ws_size,
                              hipStream_t stream)
{
    const void* x   = d_in[0];
    const void* W1  = d_in[1];
    const void* b1  = d_in[2];
    const void* W2  = d_in[3];
    const void* b2  = d_in[4];
    const int* esrc = (const int*)d_in[5];
    const int* edst = (const int*)d_in[6];
    const void* ev  = d_in[7];

    // workspace layout
    u16*   XW      = (u16*)d_ws;                            // bf16 N*NHID (12.8MB)
    int2*  temp    = (int2*)((char*)d_ws + (size_t)N_NODES * NHID * 2); // 12.8MB
    float* H1      = (float*)d_ws + (size_t)N_NODES * NHID; // f32 N*NHID (25.6MB)
    u16*   HW      = (u16*)((float*)d_ws + 2 * (size_t)N_NODES * NHID); // stride 40
    float* region  = (float*)d_ws + 2 * (size_t)N_NODES * NHID
                                  + (size_t)N_NODES * NCLASS;
    int2*  erec    = (int2*)region;                        // NEDGE int2 (12.8MB)
    int*   cnt     = (int*)(erec + NEDGE);                 // N
    int*   row_ptr = cnt + N_NODES;                        // N+1
    int*   wcur    = row_ptr + N_NODES + 1;                // N
    int*   FLAG    = wcur + N_NODES;                       // 1
    int*   bcur    = FLAG + 1;                             // NBUCK

    // Split+swizzled W1^T (2 x 128 KB) parked in the HW region: written by
    // w1t_prep, consumed by gemm1_mfma (both before gemm2 writes HW).
    u16* Wt_hi = (u16*)HW;
    u16* Wt_lo = Wt_hi + 65536;

    (void)hipMemsetAsync(cnt, 0, (size_t)N_NODES * sizeof(int), stream);

    detect_kernel<<<1, 256, 0, stream>>>(x, FLAG);

    w1t_prep_kernel<<<256, 256, 0, stream>>>(W1, Wt_hi, Wt_lo, FLAG);

    count_kernel<<<NEDGE / 256, 256, 0, stream>>>(edst, cnt);
    scan_kernel<<<1, 1024, 0, stream>>>(cnt, row_ptr, wcur);
    binit_kernel<<<1, 512, 0, stream>>>(row_ptr, bcur);
    binA_kernel<<<(NEDGE + 8191) / 8192, 512, 0, stream>>>(esrc, edst, ev,
                                                           bcur, temp, FLAG);
    binB_kernel<<<NBUCK, 256, 0, stream>>>(temp, row_ptr, wcur, erec);

    gemm1_mfma_kernel<<<256, 512, 0, stream>>>(x, Wt_hi, Wt_lo, XW, FLAG);

    spmm1_gather_kernel<<<N_NODES / 4, 256, 0, stream>>>(row_ptr, erec,
                                                         XW, b1, H1, FLAG);

    gemm2_kernel<<<N_NODES / 4, 256, 0, stream>>>(H1, W2, HW, FLAG);

    spmm2_gather_kernel<<<N_NODES / 4, 256, 0, stream>>>(row_ptr, erec,
                                                         HW, b2, d_out, FLAG);
}

// Round 7
// 545.348 us; speedup vs baseline: 2.3438x; 1.2197x over previous
//
#include <hip/hip_runtime.h>
#include <hip/hip_bf16.h>
#include <math.h>

// GCN forward: log_softmax(spmm(relu(spmm(x@W1)+b1) @ W2) + b2)
// Round 10: scan_kernel was the top dispatch (128us!): single block, occupancy
// 0.15%, 20 barriers, strided loads -- pure serialization. Replaced with a
// grid-parallel two-kernel scan:
//   scanA: 98 blocks x 512, coalesced chunk loads, LDS tree-reduce -> bsum[98]
//   scanC: 98 blocks x 512, LDS block-scan + predecessor-sum base, writes
//          row_ptr + wcur (+ row_ptr[N]).
// Everything else unchanged (three-phase MLP spmm gathers r9, binned scatter
// r8, split-bf16 MFMA gemm1 r6, bf16 XW/HW r7).

#define N_NODES 50000
#define NFEAT   512
#define NHID    128
#define NCLASS  40
#define NEDGE   1600000
#define NBUCK   391              // ceil(50000/128)
#define NSCAN   98               // ceil(50000/512)

typedef unsigned short u16;
typedef unsigned int   u32;
typedef __attribute__((ext_vector_type(8))) short bf16x8;
typedef __attribute__((ext_vector_type(4))) float f32x4;

__device__ __forceinline__ float ldf(const void* p, size_t i, int f32) {
    return f32 ? ((const float*)p)[i]
               : __bfloat162float(((const __hip_bfloat16*)p)[i]);
}

__device__ __forceinline__ u16 f2b(float f) {
    __hip_bfloat16 h = __float2bfloat16(f);
    return *(const u16*)&h;
}
__device__ __forceinline__ float b2f(u32 bits) {
    return __uint_as_float(bits << 16);
}

__global__ __launch_bounds__(256) void detect_kernel(
    const void* __restrict__ x, int* __restrict__ flag)
{
    __shared__ int bad;
    if (threadIdx.x == 0) bad = 0;
    __syncthreads();
    float v = __bfloat162float(((const __hip_bfloat16*)x)[threadIdx.x]);
    if (!(v > -100.f && v < 100.f)) atomicAdd(&bad, 1);
    __syncthreads();
    if (threadIdx.x == 0) *flag = (bad >= 4) ? 1 : 0;   // 1 => fp32
}

// ---- CSR build --------------------------------------------------------------

__global__ __launch_bounds__(256) void count_kernel(
    const int* __restrict__ edst, int* __restrict__ cnt)
{
    const int e = blockIdx.x * 256 + threadIdx.x;
    if (e < NEDGE) atomicAdd(&cnt[edst[e]], 1);
}

// grid-parallel scan, level A: per-block (512-chunk) sums
__global__ __launch_bounds__(512) void scanA_kernel(
    const int* __restrict__ cnt, int* __restrict__ bsum)
{
    __shared__ int red[512];
    const int tid = threadIdx.x;
    const int idx = blockIdx.x * 512 + tid;
    red[tid] = (idx < N_NODES) ? cnt[idx] : 0;
    __syncthreads();
    #pragma unroll
    for (int off = 256; off > 0; off >>= 1) {
        if (tid < off) red[tid] += red[tid + off];
        __syncthreads();
    }
    if (tid == 0) bsum[blockIdx.x] = red[0];
}

// level C: block base = sum of predecessor bsums; LDS block-scan of chunk
__global__ __launch_bounds__(512) void scanC_kernel(
    const int* __restrict__ cnt, const int* __restrict__ bsum,
    int* __restrict__ row_ptr, int* __restrict__ wcur)
{
    __shared__ int part[512];
    __shared__ int bs[128];
    const int tid = threadIdx.x;
    const int idx = blockIdx.x * 512 + tid;
    if (tid < 128) bs[tid] = (tid < NSCAN) ? bsum[tid] : 0;
    const int v = (idx < N_NODES) ? cnt[idx] : 0;
    part[tid] = v;
    __syncthreads();
    int base = 0;
    for (int i = 0; i < blockIdx.x; ++i) base += bs[i];
    #pragma unroll
    for (int off = 1; off < 512; off <<= 1) {
        const int t = (tid >= off) ? part[tid - off] : 0;
        __syncthreads();
        part[tid] += t;
        __syncthreads();
    }
    const int excl = base + part[tid] - v;   // exclusive prefix
    if (idx < N_NODES) {
        row_ptr[idx] = excl;
        wcur[idx]    = excl;
    }
    if (idx == N_NODES - 1) row_ptr[N_NODES] = excl + v;
}

// bucket cursors: bcur[b] = row_ptr[b*128]
__global__ __launch_bounds__(512) void binit_kernel(
    const int* __restrict__ row_ptr, int* __restrict__ bcur)
{
    const int t = threadIdx.x;
    if (t < NBUCK) bcur[t] = row_ptr[t * 128];
}

// Pass A: bin edges into 391 buckets; block-exclusive contiguous runs in temp.
// record: x = src | (dst&127)<<16  (src<65536, 7-bit row-in-bucket), y = val
__global__ __launch_bounds__(512) void binA_kernel(
    const int* __restrict__ esrc, const int* __restrict__ edst,
    const void* __restrict__ ev, int* __restrict__ bcur,
    int2* __restrict__ temp, const int* __restrict__ flag)
{
    __shared__ int hist[NBUCK], gbase[NBUCK], loff[NBUCK];
    const int f32 = *flag;
    const int tid = threadIdx.x;
    const int e0  = blockIdx.x * 8192 + tid;

    if (tid < NBUCK) hist[tid] = 0;
    __syncthreads();

    int dsts[16];
    #pragma unroll
    for (int i = 0; i < 16; ++i) {
        const int e = e0 + i * 512;
        dsts[i] = (e < NEDGE) ? edst[e] : -1;
        if (dsts[i] >= 0) atomicAdd(&hist[dsts[i] >> 7], 1);
    }
    __syncthreads();

    if (tid < NBUCK) {
        loff[tid]  = 0;
        gbase[tid] = hist[tid] ? atomicAdd(&bcur[tid], hist[tid]) : 0;
    }
    __syncthreads();

    #pragma unroll
    for (int i = 0; i < 16; ++i) {
        if (dsts[i] >= 0) {
            const int e = e0 + i * 512;
            const int b = dsts[i] >> 7;
            const int o = atomicAdd(&loff[b], 1);
            temp[gbase[b] + o] =
                make_int2(esrc[e] | ((dsts[i] & 127) << 16),
                          __float_as_int(ldf(ev, e, f32)));
        }
    }
}

// Pass B: one block per bucket; exact CSR placement inside a 32KB window.
__global__ __launch_bounds__(256) void binB_kernel(
    const int2* __restrict__ temp, const int* __restrict__ row_ptr,
    int* __restrict__ wcur, int2* __restrict__ erec)
{
    const int b = blockIdx.x;
    const int s = row_ptr[b * 128];
    const int eidx = (b + 1) * 128;
    const int en = row_ptr[eidx > N_NODES ? N_NODES : eidx];
    for (int j = s + threadIdx.x; j < en; j += 256) {
        const int2 r = temp[j];
        const int dst = (b << 7) + ((r.x >> 16) & 127);
        const int pos = atomicAdd(&wcur[dst], 1);
        erec[pos] = make_int2(r.x & 0xFFFF, r.y);
    }
}

// ---- gemm1: split-bf16 MFMA -------------------------------------------------

// W1[512][128] (f32 or bf16) -> Wt_hi/Wt_lo, swizzled per K-quarter:
//   Wt[q*16384 + c*128 + ((k&127) ^ ((c&7)<<3))] = split(W1[k][c]), q = k>>7
__global__ __launch_bounds__(256) void w1t_prep_kernel(
    const void* __restrict__ W1, u16* __restrict__ Wt_hi,
    u16* __restrict__ Wt_lo, const int* __restrict__ flag)
{
    const int f32 = *flag;
    const int e = blockIdx.x * 256 + threadIdx.x;   // grid 256 -> 65536 elems
    const int k = e >> 7, c = e & 127;
    const int q = k >> 7, kq = k & 127;
    const float v = ldf(W1, e, f32);
    __hip_bfloat16 h = __float2bfloat16(v);
    __hip_bfloat16 l = __float2bfloat16(v - __bfloat162float(h));
    const int idx = q * 16384 + c * 128 + (kq ^ ((c & 7) << 3));
    Wt_hi[idx] = *(const u16*)&h;
    Wt_lo[idx] = *(const u16*)&l;
}

__device__ __forceinline__ void async16(const u16* g, u16* l) {
    __builtin_amdgcn_global_load_lds(
        (const __attribute__((address_space(1))) void*)g,
        (__attribute__((address_space(3))) void*)l, 16, 0, 0);
}

__device__ __forceinline__ void split8(const float* p, bf16x8& hi, bf16x8& lo) {
    float t[8];
    *(float4*)&t[0] = *(const float4*)p;
    *(float4*)&t[4] = *(const float4*)(p + 4);
    #pragma unroll
    for (int j = 0; j < 8; ++j) {
        __hip_bfloat16 h = __float2bfloat16(t[j]);
        float r = t[j] - __bfloat162float(h);
        __hip_bfloat16 l = __float2bfloat16(r);
        hi[j] = *(const short*)&h;
        lo[j] = *(const short*)&l;
    }
}

// 256 blocks x 512 threads (8 waves). wave = 32 rows (2 x 16-row tiles),
// all 128 cols. chunk = blockIdx + 256*wave covers ceil(50000/32)=1563 chunks.
__global__ __launch_bounds__(512) void gemm1_mfma_kernel(
    const void* __restrict__ x, const u16* __restrict__ Wt_hi,
    const u16* __restrict__ Wt_lo, u16* __restrict__ XW,
    const int* __restrict__ flag)
{
    __shared__ u16 whi[16384];             // 32 KB: K-quarter of W_hi^T (swz)
    __shared__ u16 wlo[16384];             // 32 KB: K-quarter of W_lo^T (swz)
    const int f32  = *flag;
    const int tid  = threadIdx.x;
    const int wave = tid >> 6;
    const int lane = tid & 63;
    const int g    = lane >> 4;            // k-subgroup 0..3
    const int r16  = lane & 15;
    const int chunk = blockIdx.x + 256 * wave;
    const long row0 = (long)chunk * 32;
    const int  v0 = (row0 < N_NODES);          // 50000 = 32*1562 + 16
    const int  v1 = (row0 + 16 < N_NODES);
    const int  swz = (r16 & 7) << 3;
    const float* xf = (const float*)x;
    const u16*   xb = (const u16*)x;

    f32x4 acc0[8], acc1[8];
    #pragma unroll
    for (int c = 0; c < 8; ++c) {
        acc0[c] = (f32x4){0.f, 0.f, 0.f, 0.f};
        acc1[c] = (f32x4){0.f, 0.f, 0.f, 0.f};
    }

    for (int q = 0; q < 4; ++q) {
        if (q) __syncthreads();            // prev-quarter reads done
        #pragma unroll
        for (int s = 0; s < 4; ++s) {
            const int seg = wave + s * 8;  // 32 segments x 512 u16 (1 KB)
            async16(Wt_hi + q * 16384 + seg * 512 + lane * 8, &whi[seg * 512]);
            async16(Wt_lo + q * 16384 + seg * 512 + lane * 8, &wlo[seg * 512]);
        }
        __syncthreads();                   // drains vmcnt before ds_read

        if (v0) {
            #pragma unroll
            for (int tl = 0; tl < 4; ++tl) {
                const int kq = tl * 32 + g * 8;          // k within quarter
                const size_t kO = (size_t)q * 128 + kq;  // k within 512
                bf16x8 a0h = {0,0,0,0,0,0,0,0}, a0l = {0,0,0,0,0,0,0,0};
                bf16x8 a1h = {0,0,0,0,0,0,0,0}, a1l = {0,0,0,0,0,0,0,0};
                if (f32) {
                    split8(xf + (size_t)(row0 + r16) * NFEAT + kO, a0h, a0l);
                    if (v1)
                        split8(xf + (size_t)(row0 + 16 + r16) * NFEAT + kO,
                               a1h, a1l);
                } else {
                    a0h = *(const bf16x8*)(xb + (size_t)(row0 + r16) * NFEAT + kO);
                    if (v1)
                        a1h = *(const bf16x8*)
                            (xb + (size_t)(row0 + 16 + r16) * NFEAT + kO);
                }
                const int kb = kq ^ swz;
                #pragma unroll
                for (int c = 0; c < 8; ++c) {
                    const bf16x8 bh = *(const bf16x8*)&whi[(c * 16 + r16) * 128 + kb];
                    acc0[c] = __builtin_amdgcn_mfma_f32_16x16x32_bf16(
                        a0h, bh, acc0[c], 0, 0, 0);
                    acc1[c] = __builtin_amdgcn_mfma_f32_16x16x32_bf16(
                        a1h, bh, acc1[c], 0, 0, 0);
                    if (f32) {
                        const bf16x8 bl = *(const bf16x8*)&wlo[(c * 16 + r16) * 128 + kb];
                        acc0[c] = __builtin_amdgcn_mfma_f32_16x16x32_bf16(
                            a0l, bh, acc0[c], 0, 0, 0);
                        acc0[c] = __builtin_amdgcn_mfma_f32_16x16x32_bf16(
                            a0h, bl, acc0[c], 0, 0, 0);
                        acc1[c] = __builtin_amdgcn_mfma_f32_16x16x32_bf16(
                            a1l, bh, acc1[c], 0, 0, 0);
                        acc1[c] = __builtin_amdgcn_mfma_f32_16x16x32_bf16(
                            a1h, bl, acc1[c], 0, 0, 0);
                    }
                }
            }
        }
    }

    // C/D layout (m89-verified): col = lane&15, row = (lane>>4)*4 + reg
    if (v0) {
        #pragma unroll
        for (int c = 0; c < 8; ++c)
            #pragma unroll
            for (int r = 0; r < 4; ++r)
                XW[(size_t)(row0 + g * 4 + r) * NHID + c * 16 + r16] =
                    f2b(acc0[c][r]);
    }
    if (v1) {
        #pragma unroll
        for (int c = 0; c < 8; ++c)
            #pragma unroll
            for (int r = 0; r < 4; ++r)
                XW[(size_t)(row0 + 16 + g * 4 + r) * NHID + c * 16 + r16] =
                    f2b(acc1[c][r]);
    }
}

// ---- sparse + tail compute --------------------------------------------------

// one wave per dst row; lane holds 2 feats (one u32 = 2 bf16).
// Three-phase batches of 8: all erec loads -> all gathers -> FMA, in
// separated loops so 8 gathers stay in flight.
__global__ __launch_bounds__(256) void spmm1_gather_kernel(
    const int* __restrict__ row_ptr, const int2* __restrict__ erec,
    const u16* __restrict__ XW, const void* __restrict__ b1,
    float* __restrict__ H1, const int* __restrict__ flag)
{
    const int f32 = *flag;
    const int wave = threadIdx.x >> 6;
    const int lane = threadIdx.x & 63;
    const int row = blockIdx.x * 4 + wave;
    const int beg = row_ptr[row], end = row_ptr[row + 1];
    const u32* XWu = (const u32*)XW;       // row stride 64 u32

    float2 acc[4];
    #pragma unroll
    for (int u = 0; u < 4; ++u) acc[u] = (float2){0.f, 0.f};

    int j = beg;
    for (; j + 8 <= end; j += 8) {
        int2 e[8];
        #pragma unroll
        for (int u = 0; u < 8; ++u) e[u] = erec[j + u];
        u32 p[8];
        #pragma unroll
        for (int u = 0; u < 8; ++u) p[u] = XWu[((size_t)e[u].x << 6) + lane];
        #pragma unroll
        for (int u = 0; u < 8; ++u) {
            const float v = __int_as_float(e[u].y);
            acc[u & 3].x += v * b2f(p[u] & 0xffffu);
            acc[u & 3].y += v * b2f(p[u] >> 16);
        }
    }
    for (; j < end; ++j) {
        const int2 e = erec[j];
        const u32 p = XWu[((size_t)e.x << 6) + lane];
        const float v = __int_as_float(e.y);
        acc[0].x += v * b2f(p & 0xffffu);
        acc[0].y += v * b2f(p >> 16);
    }
    float ax = (acc[0].x + acc[1].x) + (acc[2].x + acc[3].x);
    float ay = (acc[0].y + acc[1].y) + (acc[2].y + acc[3].y);
    ax = fmaxf(ax + ldf(b1, lane * 2 + 0, f32), 0.f);
    ay = fmaxf(ay + ldf(b1, lane * 2 + 1, f32), 0.f);
    ((float2*)H1)[(size_t)row * 64 + lane] = (float2){ax, ay};
}

// 4 rows/block (wave per row): HW = H1 @ W2, stored bf16, stride 40 (4.0 MB)
__global__ __launch_bounds__(256) void gemm2_kernel(
    const float* __restrict__ H1,
    const void* __restrict__ W2,
    u16* __restrict__ HW,
    const int* __restrict__ flag)
{
    __shared__ float hs[4][NHID];
    const int f32 = *flag;
    const int wave = threadIdx.x >> 6;
    const int lane = threadIdx.x & 63;
    const int row = blockIdx.x * 4 + wave;
    const float2 h = ((const float2*)H1)[(size_t)row * 64 + lane];
    hs[wave][lane * 2 + 0] = h.x;
    hs[wave][lane * 2 + 1] = h.y;
    __syncthreads();
    if (lane < NCLASS) {
        float acc = 0.f;
        #pragma unroll 8
        for (int k = 0; k < NHID; ++k)
            acc += hs[wave][k] * ldf(W2, (size_t)k * NCLASS + lane, f32);
        HW[(size_t)row * NCLASS + lane] = f2b(acc);
    }
}

// one wave per dst row; three-phase batches of 16; fused +b2 and log_softmax
__global__ __launch_bounds__(256) void spmm2_gather_kernel(
    const int* __restrict__ row_ptr, const int2* __restrict__ erec,
    const u16* __restrict__ HW, const void* __restrict__ b2,
    void* __restrict__ out, const int* __restrict__ flag)
{
    const int f32 = *flag;
    const int wave = threadIdx.x >> 6;
    const int lane = threadIdx.x & 63;
    const int row = blockIdx.x * 4 + wave;
    const int beg = row_ptr[row], end = row_ptr[row + 1];
    const int cls = (lane < NCLASS);

    float acc[4];
    #pragma unroll
    for (int u = 0; u < 4; ++u) acc[u] = 0.f;

    int j = beg;
    for (; j + 16 <= end; j += 16) {
        int2 e[16];
        #pragma unroll
        for (int u = 0; u < 16; ++u) e[u] = erec[j + u];
        u16 h[16];
        #pragma unroll
        for (int u = 0; u < 16; ++u)
            h[u] = cls ? HW[(size_t)e[u].x * NCLASS + lane] : (u16)0;
        #pragma unroll
        for (int u = 0; u < 16; ++u)
            acc[u & 3] += __int_as_float(e[u].y) * b2f((u32)h[u]);
    }
    for (; j < end; ++j) {
        const int2 e = erec[j];
        if (cls)
            acc[0] += __int_as_float(e.y) *
                      b2f((u32)HW[(size_t)e.x * NCLASS + lane]);
    }
    const float a = (acc[0] + acc[1]) + (acc[2] + acc[3]);

    const float logit = cls ? a + ldf(b2, lane, f32) : -INFINITY;
    float m = logit;
    #pragma unroll
    for (int o = 32; o >= 1; o >>= 1) m = fmaxf(m, __shfl_xor(m, o));
    float ex = cls ? expf(logit - m) : 0.f;
    float sm = ex;
    #pragma unroll
    for (int o = 32; o >= 1; o >>= 1) sm += __shfl_xor(sm, o);
    if (cls) {
        const float r = logit - m - logf(sm);
        const size_t idx = (size_t)row * NCLASS + lane;
        if (f32) ((float*)out)[idx] = r;
        else     ((__hip_bfloat16*)out)[idx] = __float2bfloat16(r);
    }
}

extern "C" void kernel_launch(void* const* d_in, const int* in_sizes, int n_in,
                              void* d_out, int out_size, void* d_ws, size_t ws_size,
                              hipStream_t stream)
{
    const void* x   = d_in[0];
    const void* W1  = d_in[1];
    const void* b1  = d_in[2];
    const void* W2  = d_in[3];
    const void* b2  = d_in[4];
    const int* esrc = (const int*)d_in[5];
    const int* edst = (const int*)d_in[6];
    const void* ev  = d_in[7];

    // workspace layout
    u16*   XW      = (u16*)d_ws;                            // bf16 N*NHID (12.8MB)
    int2*  temp    = (int2*)((char*)d_ws + (size_t)N_NODES * NHID * 2); // 12.8MB
    float* H1      = (float*)d_ws + (size_t)N_NODES * NHID; // f32 N*NHID (25.6MB)
    u16*   HW      = (u16*)((float*)d_ws + 2 * (size_t)N_NODES * NHID); // stride 40
    float* region  = (float*)d_ws + 2 * (size_t)N_NODES * NHID
                                  + (size_t)N_NODES * NCLASS;
    int2*  erec    = (int2*)region;                        // NEDGE int2 (12.8MB)
    int*   cnt     = (int*)(erec + NEDGE);                 // N
    int*   row_ptr = cnt + N_NODES;                        // N+1
    int*   wcur    = row_ptr + N_NODES + 1;                // N
    int*   FLAG    = wcur + N_NODES;                       // 1
    int*   bcur    = FLAG + 1;                             // NBUCK
    int*   bsum    = bcur + NBUCK;                         // NSCAN

    // Split+swizzled W1^T (2 x 128 KB) parked in the HW region: written by
    // w1t_prep, consumed by gemm1_mfma (both before gemm2 writes HW).
    u16* Wt_hi = (u16*)HW;
    u16* Wt_lo = Wt_hi + 65536;

    (void)hipMemsetAsync(cnt, 0, (size_t)N_NODES * sizeof(int), stream);

    detect_kernel<<<1, 256, 0, stream>>>(x, FLAG);

    w1t_prep_kernel<<<256, 256, 0, stream>>>(W1, Wt_hi, Wt_lo, FLAG);

    count_kernel<<<NEDGE / 256, 256, 0, stream>>>(edst, cnt);
    scanA_kernel<<<NSCAN, 512, 0, stream>>>(cnt, bsum);
    scanC_kernel<<<NSCAN, 512, 0, stream>>>(cnt, bsum, row_ptr, wcur);
    binit_kernel<<<1, 512, 0, stream>>>(row_ptr, bcur);
    binA_kernel<<<(NEDGE + 8191) / 8192, 512, 0, stream>>>(esrc, edst, ev,
                                                           bcur, temp, FLAG);
    binB_kernel<<<NBUCK, 256, 0, stream>>>(temp, row_ptr, wcur, erec);

    gemm1_mfma_kernel<<<256, 512, 0, stream>>>(x, Wt_hi, Wt_lo, XW, FLAG);

    spmm1_gather_kernel<<<N_NODES / 4, 256, 0, stream>>>(row_ptr, erec,
                                                         XW, b1, H1, FLAG);

    gemm2_kernel<<<N_NODES / 4, 256, 0, stream>>>(H1, W2, HW, FLAG);

    spmm2_gather_kernel<<<N_NODES / 4, 256, 0, stream>>>(row_ptr, erec,
                                                         HW, b2, d_out, FLAG);
}